// Round 10
// baseline (760.675 us; speedup 1.0000x reference)
//
#include <hip/hip_runtime.h>
#include <math.h>

// Problem constants
#define BB    4096   // batch
#define LL    30     // seq len
#define WW    5      // window
#define CC    40     // conv channels
#define HH    128    // lstm units
#define TT    3      // crf tags
#define KA    328    // 200 (features) + 128 (h)
#define NB    32     // batch rows per LSTM block
#define NT_   768    // threads per block (R26: 12 waves -> 3 waves/SIMD -> 170 regs/wave)
#define FSTR  232    // F row stride (u16): 7 K-chunks = 224 cols (200 real + 24 pad)
#define HSTR  136    // H row stride (u16): 128 cols + pad (16B-aligned rows)
#define CW    1056   // per-column W footprint in ushorts: 11 Ks * 3 s * 32 k

// Workspace layout (in floats)
#define WS_P    0                         // P'[3][30][40] conv collapsed + bn1 folded
#define WS_BC   3600                      // biasC[40]
#define WS_BG   3648                      // biasG[2][512]
#define WS_WFC  4672                      // Wfc[2][3][128]  (fc folded with bn2)
#define WS_EB   5440                      // ebias[3]
#define WS_WBF  5504                      // bf16 W [d][n][Ks][s][32]: 540672 floats
#define WS_EMIS (5504 + 540672)           // emis[2][B][L][3] partial emissions

typedef __bf16 bf16x8 __attribute__((ext_vector_type(8)));
typedef float  f32x4  __attribute__((ext_vector_type(4)));
typedef unsigned short u16x8 __attribute__((ext_vector_type(8)));

__device__ __forceinline__ float sigm(float x) {
    return __builtin_amdgcn_rcpf(1.0f + __expf(-x));
}
__device__ __forceinline__ float tanh_fast(float x) {
    return 2.0f * __builtin_amdgcn_rcpf(1.0f + __expf(-2.0f * x)) - 1.0f;
}
// bf16 round-to-nearest-even helpers
__device__ __forceinline__ unsigned short f2bf(float f) {
    unsigned u = __builtin_bit_cast(unsigned, f);
    return (unsigned short)((u + 0x7FFFu + ((u >> 16) & 1u)) >> 16);
}
__device__ __forceinline__ float bf2f(unsigned short h) {
    unsigned u = ((unsigned)h) << 16;
    return __builtin_bit_cast(float, u);
}

// ---------------------------------------------------------------------------
// Kernel 1: fold BN1 into conv tables, 3-term split-bf16 repack of LSTM
// weights ([d][n][Ks][s][32]), fold BN2 into FC. (unchanged)
// ---------------------------------------------------------------------------
__global__ void prep_kernel(const float* __restrict__ emb, const float* __restrict__ conv_w,
                            const float* __restrict__ conv_b,
                            const float* __restrict__ bn1_g, const float* __restrict__ bn1_b,
                            const float* __restrict__ bn1_m, const float* __restrict__ bn1_v,
                            const float* __restrict__ w_ih_f, const float* __restrict__ w_hh_f,
                            const float* __restrict__ b_f,
                            const float* __restrict__ w_ih_b, const float* __restrict__ w_hh_b,
                            const float* __restrict__ b_b,
                            const float* __restrict__ bn2_g, const float* __restrict__ bn2_b,
                            const float* __restrict__ bn2_m, const float* __restrict__ bn2_v,
                            const float* __restrict__ fc_w, const float* __restrict__ fc_b,
                            float* __restrict__ ws)
{
    const int gid = blockIdx.x * blockDim.x + threadIdx.x;
    const int gsz = gridDim.x * blockDim.x;

    for (int idx = gid; idx < 3600; idx += gsz) {
        int k = idx / 1200, rem = idx % 1200, a = rem / 40, c = rem % 40;
        float s1 = bn1_g[c] / sqrtf(bn1_v[c] + 1e-5f);
        float acc = 0.f;
        for (int e = 0; e < 128; ++e)
            acc += emb[a * 128 + e] * conv_w[(c * 128 + e) * 3 + k];
        ws[WS_P + idx] = acc * s1;
    }
    for (int c = gid; c < CC; c += gsz) {
        float s1 = bn1_g[c] / sqrtf(bn1_v[c] + 1e-5f);
        ws[WS_BC + c] = (conv_b[c] - bn1_m[c]) * s1 + bn1_b[c];
    }
    for (int i = gid; i < 1024; i += gsz) {
        int d = i >> 9, g = i & 511;
        ws[WS_BG + i] = d ? b_b[g] : b_f[g];
    }
    for (int i = gid; i < 768; i += gsz) {
        int d = i / 384, r = i % 384, t = r / 128, u = r % 128;
        int j = d * 128 + u;
        float s2 = bn2_g[j] / sqrtf(bn2_v[j] + 1e-5f);
        ws[WS_WFC + i] = fc_w[t * 256 + j] * s2;
    }
    for (int t = gid; t < TT; t += gsz) {
        float acc = fc_b[t];
        for (int j = 0; j < 256; ++j) {
            float s2 = bn2_g[j] / sqrtf(bn2_v[j] + 1e-5f);
            acc += fc_w[t * 256 + j] * (bn2_b[j] - bn2_m[j] * s2);
        }
        ws[WS_EB + t] = acc;
    }
    // Wbf[d][n][Ks][s][32]: n = 4u+g; per column all Ks/s chunks contiguous.
    unsigned short* wsu = (unsigned short*)ws;
    for (int i = gid; i < 2 * 512 * CW; i += gsz) {
        int d = i / (512 * CW), r = i % (512 * CW);
        int n = r / CW, q = r % CW;
        int Ks = q / 96, t = q % 96, s = t / 32, k32 = t % 32;
        int k = Ks * 32 + k32;
        int u = n >> 2, g = n & 3, row = g * 128 + u;
        const float* wih = d ? w_ih_b : w_ih_f;
        const float* whh = d ? w_hh_b : w_hh_f;
        float w = (k < 200) ? wih[row * 200 + k]
                            : ((k >= 224) ? whh[row * 128 + (k - 224)] : 0.f);
        unsigned short t0 = f2bf(w);
        float r1 = w - bf2f(t0);
        unsigned short t1 = f2bf(r1);
        unsigned short t2 = f2bf(r1 - bf2f(t1));
        wsu[2 * WS_WBF + i] = (s == 0) ? t0 : ((s == 1) ? t1 : t2);
    }
}

// ---------------------------------------------------------------------------
// Kernel 2: fused features + BiLSTM (3-term split-bf16 MFMA) + emissions.
// R26: 768 threads / 12 waves = 3 waves/SIMD (170 regs/wave; R23's pipeline
// measures 120 VGPR so it fits). Per-SIMD budgets: MFMA 20.5K cyc/step,
// W-from-L2 19.3K, VALU 12K — R23's measured step (50.5K) ~= the SUM, i.e.
// near-zero overlap, because 2 waves/SIMD give no TLP slack. A 3rd wave
// covers stalls. 32 nt-tiles split 8 waves x 3 + 4 waves x 2; light waves
// {2,3,8,9} chosen so BOTH wave->SIMD mappings (mod-4 and div-3) give every
// SIMD exactly 8 tiles. Light waves carry 3 FEAT items + EMIS (waves 2,3,8);
// heavy 1 FEAT item. Heavy K-loop: 3-tile ring on 2 named buffers (slot
// parity static after unroll); light: R23's 2-tile ping-pong. Per-column
// chain order identical to R23 -> bitwise-identical numerics.
// LDS 157,408 B (1 block/CU). Spill canary: FETCH_SIZE.
// ---------------------------------------------------------------------------
__global__ __launch_bounds__(768, 3)
void lstm_kernel(const int* __restrict__ x, float* __restrict__ ws)
{
    __shared__ unsigned short Fh[2][NB * FSTR], Fl[2][NB * FSTR], Fm[2][NB * FSTR];
    __shared__ unsigned short Hh[2][NB * HSTR], Hl[2][NB * HSTR], Hm[2][NB * HSTR];
    __shared__ float Pp_s[3600];
    __shared__ float Wfc_s[384];
    __shared__ float biasC_s[40];

    const int tid = threadIdx.x;
    const int d   = blockIdx.x & 1;
    const int b0  = (blockIdx.x >> 1) * NB;

    const unsigned short* __restrict__ Wb =
        (const unsigned short*)ws + 2 * WS_WBF + d * (512 * CW);
    float* emis = ws + WS_EMIS + d * (BB * LL * TT);

    for (int i = tid; i < 3600; i += NT_) Pp_s[i] = ws[WS_P + i];
    for (int i = tid; i < 384;  i += NT_) Wfc_s[i] = ws[WS_WFC + d * 384 + i];
    for (int i = tid; i < 40;   i += NT_) biasC_s[i] = ws[WS_BC + i];
    // zero F (both buffers; covers K pads) and H (both buffers; h_{-1}=0)
    for (int i = tid; i < NB * FSTR; i += NT_) {
        ((unsigned*)Fh)[i] = 0u; ((unsigned*)Fl)[i] = 0u; ((unsigned*)Fm)[i] = 0u;
    }
    for (int i = tid; i < NB * HSTR; i += NT_) {
        ((unsigned*)Hh)[i] = 0u; ((unsigned*)Hl)[i] = 0u; ((unsigned*)Hm)[i] = 0u;
    }

    const int lane = tid & 63;
    const int wv   = tid >> 6;          // 0..11
    const int quad = lane >> 4;
    const int ml   = lane & 15;

    // light waves (2 tiles): {2,3,8,9}; heavy (3 tiles): the rest.
    const int lightw = (wv == 2) | (wv == 3) | (wv == 8) | (wv == 9);
    // TILE base / 64 in units of... tb4 = first unit index (col base / 4)
    const int tb4 = (wv == 0) ? 0 : (wv == 1) ? 12 : (wv == 2) ? 24 :
                    (wv == 3) ? 32 : (wv == 4) ? 40 : (wv == 5) ? 52 :
                    (wv == 6) ? 64 : (wv == 7) ? 76 : (wv == 8) ? 88 :
                    (wv == 9) ? 96 : (wv == 10) ? 104 : 116;
    const int cb0 = tb4 * 4;            // first gate-col of this wave
    // FEAT item base: heavy waves 64 items, light 192
    const int fb0 = (wv == 0) ? 0 : (wv == 1) ? 64 : (wv == 2) ? 128 :
                    (wv == 3) ? 320 : (wv == 4) ? 512 : (wv == 5) ? 576 :
                    (wv == 6) ? 640 : (wv == 7) ? 704 : (wv == 8) ? 768 :
                    (wv == 9) ? 960 : (wv == 10) ? 1152 : 1216;
    const int it0 = fb0 + lane;

    // W tile pointers (light: Wt[2] aliased to Wt[0], never loaded)
    const unsigned short* __restrict__ Wt[3];
    Wt[0] = Wb + (cb0 +  0 + ml) * CW + quad * 8;
    Wt[1] = Wb + (cb0 + 16 + ml) * CW + quad * 8;
    Wt[2] = lightw ? Wt[0] : (Wb + (cb0 + 32 + ml) * CW + quad * 8);

    // per-nt unit ids + gate biases
    const float* bgp = ws + WS_BG + d * 512;
    int   un[3];
    float bIv[3], bFv[3], bGv[3], bOv[3];
    #pragma unroll
    for (int nt = 0; nt < 3; ++nt) {
        int u = tb4 + nt * 4 + quad;
        u = (u > 127) ? 127 : u;        // light nt=2 slot unused; keep in range
        un[nt]  = u;
        bIv[nt] = bgp[u];
        bFv[nt] = bgp[128 + u];
        bGv[nt] = bgp[256 + u];
        bOv[nt] = bgp[384 + u];
    }

    float cst[2][3];
    #pragma unroll
    for (int mt = 0; mt < 2; ++mt)
        #pragma unroll
        for (int nt = 0; nt < 3; ++nt) cst[mt][nt] = 0.f;

    __syncthreads();

    // ---- one feature item (batch bb, channel c) for seq position l ----
#define FEAT_ONE(LPOS, BUF, P)                                                 \
    {                                                                          \
        int bb = (P) / CC, c = (P) % CC;                                       \
        const int* tok = x + (((b0 + bb) * LL) + (LPOS)) * WW;                 \
        int t0 = tok[0], t1 = tok[1], t2 = tok[2], t3 = tok[3], t4 = tok[4];   \
        float bc = biasC_s[c];                                                 \
        float a0 = bc + Pp_s[(30 + t0) * 40 + c] + Pp_s[(60 + t1) * 40 + c];   \
        float a1 = bc + Pp_s[t0 * 40 + c] + Pp_s[(30 + t1) * 40 + c] + Pp_s[(60 + t2) * 40 + c]; \
        float a2 = bc + Pp_s[t1 * 40 + c] + Pp_s[(30 + t2) * 40 + c] + Pp_s[(60 + t3) * 40 + c]; \
        float a3 = bc + Pp_s[t2 * 40 + c] + Pp_s[(30 + t3) * 40 + c] + Pp_s[(60 + t4) * 40 + c]; \
        float a4 = bc + Pp_s[t3 * 40 + c] + Pp_s[(30 + t4) * 40 + c];          \
        a0 = fmaxf(a0, 0.f); a1 = fmaxf(a1, 0.f); a2 = fmaxf(a2, 0.f);         \
        a3 = fmaxf(a3, 0.f); a4 = fmaxf(a4, 0.f);                              \
        float f[5];                                                            \
        f[0] = fmaxf(a0, a1);                                                  \
        f[1] = fmaxf(fmaxf(a0, a1), a2);                                       \
        f[2] = fmaxf(fmaxf(a1, a2), a3);                                       \
        f[3] = fmaxf(fmaxf(a2, a3), a4);                                       \
        f[4] = fmaxf(a3, a4);                                                  \
        int base = bb * FSTR + c * 5;                                          \
        _Pragma("unroll")                                                      \
        for (int j = 0; j < 5; ++j) {                                          \
            unsigned short h0 = f2bf(f[j]);                                    \
            float r1 = f[j] - bf2f(h0);                                        \
            unsigned short h1 = f2bf(r1);                                      \
            unsigned short h2 = f2bf(r1 - bf2f(h1));                           \
            Fh[BUF][base + j] = h0;                                            \
            Fl[BUF][base + j] = h1;                                            \
            Fm[BUF][base + j] = h2;                                            \
        }                                                                      \
    }

    // emissions for one seq position from H buffer HB, emis-index PIDX (0..191)
#define EMIS_BODY(LPOS, HB, PIDX)                                              \
    {                                                                          \
        int bb = (PIDX) / 6, r6 = (PIDX) % 6, t = r6 >> 1, seg = r6 & 1;       \
        int hoff = bb * HSTR + seg * 64;                                       \
        const float* wfc = &Wfc_s[t * 128 + seg * 64];                         \
        float s = 0.f;                                                         \
        _Pragma("unroll")                                                      \
        for (int i = 0; i < 8; ++i) {                                          \
            u16x8 v0 = *(const u16x8*)&Hh[HB][hoff + i * 8];                   \
            u16x8 v1 = *(const u16x8*)&Hl[HB][hoff + i * 8];                   \
            u16x8 v2 = *(const u16x8*)&Hm[HB][hoff + i * 8];                   \
            _Pragma("unroll")                                                  \
            for (int j = 0; j < 8; ++j) {                                      \
                float h = bf2f(v0[j]) + bf2f(v1[j]) + bf2f(v2[j]);             \
                s += h * wfc[i * 8 + j];                                       \
            }                                                                  \
        }                                                                      \
        s += __shfl_xor(s, 1);                                                 \
        if (seg == 0)                                                          \
            emis[(((b0 + bb) * LL) + (LPOS)) * TT + t] = s;                    \
    }

#define WLOADT(B, P, KS)                                                       \
        {                                                                      \
            B[0] = *(const bf16x8*)((P) + (KS) * 96);                          \
            B[1] = *(const bf16x8*)((P) + (KS) * 96 + 32);                     \
            B[2] = *(const bf16x8*)((P) + (KS) * 96 + 64);                     \
        }
    // A-plane loads (all 3 split terms, both m-tiles) for round KS -> buf BUF
#define LDA(BUF, KS)                                                           \
        {                                                                      \
            if ((KS) < 7) {                                                    \
                const int ko_ = (KS) * 32 + quad * 8;                          \
                ah[BUF][0] = *(const bf16x8*)&Fh[fb][ml * FSTR + ko_];         \
                al[BUF][0] = *(const bf16x8*)&Fl[fb][ml * FSTR + ko_];         \
                am[BUF][0] = *(const bf16x8*)&Fm[fb][ml * FSTR + ko_];         \
                ah[BUF][1] = *(const bf16x8*)&Fh[fb][(16 + ml) * FSTR + ko_];  \
                al[BUF][1] = *(const bf16x8*)&Fl[fb][(16 + ml) * FSTR + ko_];  \
                am[BUF][1] = *(const bf16x8*)&Fm[fb][(16 + ml) * FSTR + ko_];  \
            } else {                                                           \
                const int ko_ = ((KS) - 7) * 32 + quad * 8;                    \
                ah[BUF][0] = *(const bf16x8*)&Hh[hr][ml * HSTR + ko_];         \
                al[BUF][0] = *(const bf16x8*)&Hl[hr][ml * HSTR + ko_];         \
                am[BUF][0] = *(const bf16x8*)&Hm[hr][ml * HSTR + ko_];         \
                ah[BUF][1] = *(const bf16x8*)&Hh[hr][(16 + ml) * HSTR + ko_];  \
                al[BUF][1] = *(const bf16x8*)&Hl[hr][(16 + ml) * HSTR + ko_];  \
                am[BUF][1] = *(const bf16x8*)&Hm[hr][(16 + ml) * HSTR + ko_];  \
            }                                                                  \
        }
    // D = W' * A' — same 6 products, same order per acc chain as R9-R25
#define GEMM6X(B, CB, NT)                                                      \
        {                                                                      \
            acc[0][NT] = __builtin_amdgcn_mfma_f32_16x16x32_bf16(B[0], ah[CB][0], acc[0][NT], 0, 0, 0); \
            acc[0][NT] = __builtin_amdgcn_mfma_f32_16x16x32_bf16(B[0], al[CB][0], acc[0][NT], 0, 0, 0); \
            acc[0][NT] = __builtin_amdgcn_mfma_f32_16x16x32_bf16(B[1], ah[CB][0], acc[0][NT], 0, 0, 0); \
            acc[0][NT] = __builtin_amdgcn_mfma_f32_16x16x32_bf16(B[1], al[CB][0], acc[0][NT], 0, 0, 0); \
            acc[0][NT] = __builtin_amdgcn_mfma_f32_16x16x32_bf16(B[2], ah[CB][0], acc[0][NT], 0, 0, 0); \
            acc[0][NT] = __builtin_amdgcn_mfma_f32_16x16x32_bf16(B[0], am[CB][0], acc[0][NT], 0, 0, 0); \
            acc[1][NT] = __builtin_amdgcn_mfma_f32_16x16x32_bf16(B[0], ah[CB][1], acc[1][NT], 0, 0, 0); \
            acc[1][NT] = __builtin_amdgcn_mfma_f32_16x16x32_bf16(B[0], al[CB][1], acc[1][NT], 0, 0, 0); \
            acc[1][NT] = __builtin_amdgcn_mfma_f32_16x16x32_bf16(B[1], ah[CB][1], acc[1][NT], 0, 0, 0); \
            acc[1][NT] = __builtin_amdgcn_mfma_f32_16x16x32_bf16(B[1], al[CB][1], acc[1][NT], 0, 0, 0); \
            acc[1][NT] = __builtin_amdgcn_mfma_f32_16x16x32_bf16(B[2], ah[CB][1], acc[1][NT], 0, 0, 0); \
            acc[1][NT] = __builtin_amdgcn_mfma_f32_16x16x32_bf16(B[0], am[CB][1], acc[1][NT], 0, 0, 0); \
        }
    // gates for one nt column (both mt) -> h into H[hw]
#define GATES_NT(NT)                                                           \
        {                                                                      \
            _Pragma("unroll")                                                  \
            for (int mt = 0; mt < 2; ++mt) {                                   \
                float zi = acc[mt][NT][0] + bIv[NT];                           \
                float zf = acc[mt][NT][1] + bFv[NT];                           \
                float zg = acc[mt][NT][2] + bGv[NT];                           \
                float zo = acc[mt][NT][3] + bOv[NT];                           \
                float cn = sigm(zf) * cst[mt][NT] + sigm(zi) * tanh_fast(zg);  \
                cst[mt][NT] = cn;                                              \
                float h = sigm(zo) * tanh_fast(cn);                            \
                unsigned short h0 = f2bf(h);                                   \
                float r1 = h - bf2f(h0);                                       \
                unsigned short h1 = f2bf(r1);                                  \
                unsigned short h2 = f2bf(r1 - bf2f(h1));                       \
                int idx = (mt * 16 + ml) * HSTR + un[NT];                      \
                Hh[hw][idx] = h0; Hl[hw][idx] = h1; Hm[hw][idx] = h2;          \
            }                                                                  \
        }

    // prologue: features for step 0 (heavy: 1 item, light: 3 items)
    {
        const int l0 = d ? (LL - 1) : 0;
        if (!lightw) {
            FEAT_ONE(l0, 0, it0)
        } else {
            FEAT_ONE(l0, 0, it0)
            FEAT_ONE(l0, 0, it0 + 64)
            FEAT_ONE(l0, 0, it0 + 128)
        }
    }

    // W buffers live across the step loop; prefetch tile0 Ks=0 (parity 0).
    bf16x8 wb[2][3];
    WLOADT(wb[0], Wt[0], 0)

    __syncthreads();   // F(0) + LDS init visible

    for (int step = 0; step < LL; ++step) {
        const int fb = step & 1;
        const int hw = step & 1;        // h_step is written here
        const int hr = hw ^ 1;          // h_{step-1} lives here (zeros at step 0)

        f32x4 acc[2][3];

        if (!lightw) {
            // ================= heavy: 3 tiles, slot ring on wb[2] =========
            #pragma unroll
            for (int mt = 0; mt < 2; ++mt)
                #pragma unroll
                for (int nt = 0; nt < 3; ++nt)
                    acc[mt][nt] = (f32x4){0.f, 0.f, 0.f, 0.f};

            bf16x8 ah[2][2], al[2][2], am[2][2];
            LDA(0, 0)

            #pragma unroll
            for (int Ks = 0; Ks < 11; ++Ks) {
                const int cb = Ks & 1, nb = cb ^ 1;

                WLOADT(wb[nb], Wt[1], Ks)            // slot 3Ks+1 (parity nb)
                if (Ks < 10) LDA(nb, Ks + 1)

                __builtin_amdgcn_s_setprio(1);
                GEMM6X(wb[cb], cb, 0)                // tile0 (slot 3Ks)
                __builtin_amdgcn_s_setprio(0);

                WLOADT(wb[cb], Wt[2], Ks)            // slot 3Ks+2 (parity cb)

                __builtin_amdgcn_s_setprio(1);
                GEMM6X(wb[nb], cb, 1)                // tile1
                __builtin_amdgcn_s_setprio(0);

                if (Ks < 10) WLOADT(wb[nb], Wt[0], Ks + 1)  // slot 3Ks+3 (nb)

                __builtin_amdgcn_s_setprio(1);
                GEMM6X(wb[cb], cb, 2)                // tile2
                __builtin_amdgcn_s_setprio(0);

                // single FEAT item in the shadow, spread over slots 3/5/7/9
                if (Ks == 3 && step + 1 < LL && (wv & 3) == 0) {
                    const int ln = d ? (LL - 2 - step) : (step + 1);
                    FEAT_ONE(ln, fb ^ 1, it0)
                }
                if (Ks == 5 && step + 1 < LL && (wv & 3) == 1) {
                    const int ln = d ? (LL - 2 - step) : (step + 1);
                    FEAT_ONE(ln, fb ^ 1, it0)
                }
                if (Ks == 7 && step + 1 < LL && (wv & 3) == 2) {
                    const int ln = d ? (LL - 2 - step) : (step + 1);
                    FEAT_ONE(ln, fb ^ 1, it0)
                }
                if (Ks == 9 && step + 1 < LL && (wv & 3) == 3) {
                    const int ln = d ? (LL - 2 - step) : (step + 1);
                    FEAT_ONE(ln, fb ^ 1, it0)
                }
            }

            GATES_NT(0)
            GATES_NT(1)
            GATES_NT(2)

            if (step + 1 < LL) WLOADT(wb[0], Wt[0], 0)   // next step slot 0
        } else {
            // ================= light: 2 tiles (R23 ping-pong) =============
            #pragma unroll
            for (int mt = 0; mt < 2; ++mt)
                #pragma unroll
                for (int nt = 0; nt < 2; ++nt)
                    acc[mt][nt] = (f32x4){0.f, 0.f, 0.f, 0.f};

            bf16x8 ah[2][2], al[2][2], am[2][2];
            LDA(0, 0)

            #pragma unroll
            for (int Ks = 0; Ks < 11; ++Ks) {
                const int cb = Ks & 1, nb = cb ^ 1;

                WLOADT(wb[1], Wt[1], Ks)             // tile1 this round
                if (Ks < 10) LDA(nb, Ks + 1)

                __builtin_amdgcn_s_setprio(1);
                GEMM6X(wb[0], cb, 0)                 // tile0
                __builtin_amdgcn_s_setprio(0);

                if (Ks < 10) WLOADT(wb[0], Wt[0], Ks + 1)

                __builtin_amdgcn_s_setprio(1);
                GEMM6X(wb[1], cb, 1)                 // tile1
                __builtin_amdgcn_s_setprio(0);

                // 3 FEAT items, one per slot (small bursts)
                if (Ks == 2 && step + 1 < LL) {
                    const int ln = d ? (LL - 2 - step) : (step + 1);
                    FEAT_ONE(ln, fb ^ 1, it0)
                }
                if (Ks == 5 && step + 1 < LL) {
                    const int ln = d ? (LL - 2 - step) : (step + 1);
                    FEAT_ONE(ln, fb ^ 1, it0 + 64)
                }
                if (Ks == 8 && step + 1 < LL) {
                    const int ln = d ? (LL - 2 - step) : (step + 1);
                    FEAT_ONE(ln, fb ^ 1, it0 + 128)
                }
            }

            // emissions for step-1 (waves 2,3,8; reads H[hr], gates write H[hw])
            if (step > 0 && wv != 9) {
                const int lprev = d ? (LL - step) : (step - 1);
                const int p = (wv == 8) ? (tid - 384) : (tid - 128);
                EMIS_BODY(lprev, hr, p)
            }

            GATES_NT(0)
            GATES_NT(1)

            if (step + 1 < LL) WLOADT(wb[0], Wt[0], 0)   // next step tile0
        }

        __syncthreads();   // h_step + F(t+1) visible; H[hr]/F[fb] free for reuse
    }
#undef GATES_NT
#undef GEMM6X
#undef LDA
#undef WLOADT

    // epilogue: emissions for the last step (h_{LL-1} lives in H[(LL-1)&1])
    if (lightw && wv != 9) {
        const int llast = d ? 0 : (LL - 1);
        const int hl_ = (LL - 1) & 1;
        const int p = (wv == 8) ? (tid - 384) : (tid - 128);
        EMIS_BODY(llast, hl_, p)
    }
#undef EMIS_BODY
#undef FEAT_ONE
}

// ---------------------------------------------------------------------------
// Kernel 3: Viterbi decode. One thread per batch row. (unchanged)
// ---------------------------------------------------------------------------
__global__ void viterbi_kernel(const int* __restrict__ x, const float* __restrict__ ws,
                               const float* __restrict__ trans,
                               const float* __restrict__ start_t,
                               const float* __restrict__ end_t,
                               float* __restrict__ out)
{
    int b = blockIdx.x * blockDim.x + threadIdx.x;
    if (b >= BB) return;
    const float* eF = ws + WS_EMIS;
    const float* eB = ws + WS_EMIS + BB * LL * TT;
    const float eb0 = ws[WS_EB + 0], eb1 = ws[WS_EB + 1], eb2 = ws[WS_EB + 2];
    float tr[9];
    #pragma unroll
    for (int i = 0; i < 9; ++i) tr[i] = trans[i];

    int base = b * LL * TT;
    float s0 = start_t[0] + eF[base + 0] + eB[base + 0] + eb0;
    float s1 = start_t[1] + eF[base + 1] + eB[base + 1] + eb1;
    float s2 = start_t[2] + eF[base + 2] + eB[base + 2] + eb2;

    unsigned hist[LL - 1];
    unsigned maskbits = 0;

    #pragma unroll
    for (int l = 1; l < LL; ++l) {
        bool m = x[(b * LL + l) * WW + 2] > 0;
        if (m) maskbits |= (1u << l);
        int idx = base + l * TT;
        float e0 = eF[idx + 0] + eB[idx + 0] + eb0;
        float e1 = eF[idx + 1] + eB[idx + 1] + eb1;
        float e2 = eF[idx + 2] + eB[idx + 2] + eb2;

        float ns[3]; int pt[3];
        #pragma unroll
        for (int nt = 0; nt < 3; ++nt) {
            float c0 = s0 + tr[0 * 3 + nt];
            float c1 = s1 + tr[1 * 3 + nt];
            float c2 = s2 + tr[2 * 3 + nt];
            int p = 0; float bc = c0;
            if (c1 > bc) { bc = c1; p = 1; }   // strict '>': first-index argmax
            if (c2 > bc) { bc = c2; p = 2; }
            ns[nt] = bc; pt[nt] = p;
        }
        ns[0] += e0; ns[1] += e1; ns[2] += e2;
        hist[l - 1] = (unsigned)pt[0] | ((unsigned)pt[1] << 2) | ((unsigned)pt[2] << 4);
        if (m) { s0 = ns[0]; s1 = ns[1]; s2 = ns[2]; }
    }
    s0 += end_t[0]; s1 += end_t[1]; s2 += end_t[2];
    float best = s0; int last = 0;
    if (s1 > best) { best = s1; last = 1; }
    if (s2 > best) { best = s2; last = 2; }

    out[b] = best;
    float* tags = out + BB + b * LL;
    int tag = last;
    tags[LL - 1] = (float)last;
    #pragma unroll
    for (int l = LL - 1; l >= 1; --l) {
        int prev = (int)((hist[l - 1] >> (2 * tag)) & 3u);
        if (maskbits & (1u << l)) tag = prev;
        tags[l - 1] = (float)tag;
    }
}

// ---------------------------------------------------------------------------
extern "C" void kernel_launch(void* const* d_in, const int* in_sizes, int n_in,
                              void* d_out, int out_size, void* d_ws, size_t ws_size,
                              hipStream_t stream)
{
    const int*   x      = (const int*)  d_in[0];
    const float* emb    = (const float*)d_in[1];
    const float* conv_w = (const float*)d_in[2];
    const float* conv_b = (const float*)d_in[3];
    const float* bn1_g  = (const float*)d_in[4];
    const float* bn1_b  = (const float*)d_in[5];
    const float* bn1_m  = (const float*)d_in[6];
    const float* bn1_v  = (const float*)d_in[7];
    const float* w_ih_f = (const float*)d_in[8];
    const float* w_hh_f = (const float*)d_in[9];
    const float* b_f    = (const float*)d_in[10];
    const float* w_ih_b = (const float*)d_in[11];
    const float* w_hh_b = (const float*)d_in[12];
    const float* b_b    = (const float*)d_in[13];
    const float* bn2_g  = (const float*)d_in[14];
    const float* bn2_b  = (const float*)d_in[15];
    const float* bn2_m  = (const float*)d_in[16];
    const float* bn2_v  = (const float*)d_in[17];
    const float* fc_w   = (const float*)d_in[18];
    const float* fc_b   = (const float*)d_in[19];
    const float* trans  = (const float*)d_in[20];
    const float* start_t= (const float*)d_in[21];
    const float* end_t  = (const float*)d_in[22];

    float* ws  = (float*)d_ws;
    float* out = (float*)d_out;

    prep_kernel<<<256, 256, 0, stream>>>(emb, conv_w, conv_b,
                                         bn1_g, bn1_b, bn1_m, bn1_v,
                                         w_ih_f, w_hh_f, b_f,
                                         w_ih_b, w_hh_b, b_b,
                                         bn2_g, bn2_b, bn2_m, bn2_v,
                                         fc_w, fc_b, ws);
    lstm_kernel<<<256, 768, 0, stream>>>(x, ws);
    viterbi_kernel<<<16, 256, 0, stream>>>(x, ws, trans, start_t, end_t, out);
}

// Round 11
// 729.813 us; speedup vs baseline: 1.0423x; 1.0423x over previous
//
#include <hip/hip_runtime.h>
#include <math.h>

// Problem constants
#define BB    4096   // batch
#define LL    30     // seq len
#define WW    5      // window
#define CC    40     // conv channels
#define HH    128    // lstm units
#define TT    3      // crf tags
#define KA    328    // 200 (features) + 128 (h)
#define NB    32     // batch rows per LSTM block
#define NT_   512    // threads per block (8 waves -> 2 waves/SIMD -> no spill)
#define FSTR  232    // F row stride (u16): 7 K-chunks = 224 cols (200 real + 24 pad)
#define HSTR  136    // H row stride (u16): 128 cols + pad (16B-aligned rows)
#define CW    1056   // per-column W footprint in ushorts: 11 Ks * 3 s * 32 k

// Workspace layout (in floats)
#define WS_P    0                         // P'[3][30][40] conv collapsed + bn1 folded
#define WS_BC   3600                      // biasC[40]
#define WS_BG   3648                      // biasG[2][512]
#define WS_WFC  4672                      // Wfc[2][3][128]  (fc folded with bn2)
#define WS_EB   5440                      // ebias[3]
#define WS_WBF  5504                      // bf16 W [d][n][Ks][s][32]: 540672 floats
#define WS_EMIS (5504 + 540672)           // emis[2][B][L][3] partial emissions

typedef __bf16 bf16x8 __attribute__((ext_vector_type(8)));
typedef float  f32x4  __attribute__((ext_vector_type(4)));
typedef unsigned short u16x8 __attribute__((ext_vector_type(8)));

__device__ __forceinline__ float sigm(float x) {
    return __builtin_amdgcn_rcpf(1.0f + __expf(-x));
}
__device__ __forceinline__ float tanh_fast(float x) {
    return 2.0f * __builtin_amdgcn_rcpf(1.0f + __expf(-2.0f * x)) - 1.0f;
}
// bf16 round-to-nearest-even helpers
__device__ __forceinline__ unsigned short f2bf(float f) {
    unsigned u = __builtin_bit_cast(unsigned, f);
    return (unsigned short)((u + 0x7FFFu + ((u >> 16) & 1u)) >> 16);
}
__device__ __forceinline__ float bf2f(unsigned short h) {
    unsigned u = ((unsigned)h) << 16;
    return __builtin_bit_cast(float, u);
}

// ---------------------------------------------------------------------------
// Kernel 1: fold BN1 into conv tables, 3-term split-bf16 repack of LSTM
// weights ([d][n][Ks][s][32]), fold BN2 into FC. (unchanged)
// ---------------------------------------------------------------------------
__global__ void prep_kernel(const float* __restrict__ emb, const float* __restrict__ conv_w,
                            const float* __restrict__ conv_b,
                            const float* __restrict__ bn1_g, const float* __restrict__ bn1_b,
                            const float* __restrict__ bn1_m, const float* __restrict__ bn1_v,
                            const float* __restrict__ w_ih_f, const float* __restrict__ w_hh_f,
                            const float* __restrict__ b_f,
                            const float* __restrict__ w_ih_b, const float* __restrict__ w_hh_b,
                            const float* __restrict__ b_b,
                            const float* __restrict__ bn2_g, const float* __restrict__ bn2_b,
                            const float* __restrict__ bn2_m, const float* __restrict__ bn2_v,
                            const float* __restrict__ fc_w, const float* __restrict__ fc_b,
                            float* __restrict__ ws)
{
    const int gid = blockIdx.x * blockDim.x + threadIdx.x;
    const int gsz = gridDim.x * blockDim.x;

    for (int idx = gid; idx < 3600; idx += gsz) {
        int k = idx / 1200, rem = idx % 1200, a = rem / 40, c = rem % 40;
        float s1 = bn1_g[c] / sqrtf(bn1_v[c] + 1e-5f);
        float acc = 0.f;
        for (int e = 0; e < 128; ++e)
            acc += emb[a * 128 + e] * conv_w[(c * 128 + e) * 3 + k];
        ws[WS_P + idx] = acc * s1;
    }
    for (int c = gid; c < CC; c += gsz) {
        float s1 = bn1_g[c] / sqrtf(bn1_v[c] + 1e-5f);
        ws[WS_BC + c] = (conv_b[c] - bn1_m[c]) * s1 + bn1_b[c];
    }
    for (int i = gid; i < 1024; i += gsz) {
        int d = i >> 9, g = i & 511;
        ws[WS_BG + i] = d ? b_b[g] : b_f[g];
    }
    for (int i = gid; i < 768; i += gsz) {
        int d = i / 384, r = i % 384, t = r / 128, u = r % 128;
        int j = d * 128 + u;
        float s2 = bn2_g[j] / sqrtf(bn2_v[j] + 1e-5f);
        ws[WS_WFC + i] = fc_w[t * 256 + j] * s2;
    }
    for (int t = gid; t < TT; t += gsz) {
        float acc = fc_b[t];
        for (int j = 0; j < 256; ++j) {
            float s2 = bn2_g[j] / sqrtf(bn2_v[j] + 1e-5f);
            acc += fc_w[t * 256 + j] * (bn2_b[j] - bn2_m[j] * s2);
        }
        ws[WS_EB + t] = acc;
    }
    // Wbf[d][n][Ks][s][32]: n = 4u+g; per column all Ks/s chunks contiguous.
    unsigned short* wsu = (unsigned short*)ws;
    for (int i = gid; i < 2 * 512 * CW; i += gsz) {
        int d = i / (512 * CW), r = i % (512 * CW);
        int n = r / CW, q = r % CW;
        int Ks = q / 96, t = q % 96, s = t / 32, k32 = t % 32;
        int k = Ks * 32 + k32;
        int u = n >> 2, g = n & 3, row = g * 128 + u;
        const float* wih = d ? w_ih_b : w_ih_f;
        const float* whh = d ? w_hh_b : w_hh_f;
        float w = (k < 200) ? wih[row * 200 + k]
                            : ((k >= 224) ? whh[row * 128 + (k - 224)] : 0.f);
        unsigned short t0 = f2bf(w);
        float r1 = w - bf2f(t0);
        unsigned short t1 = f2bf(r1);
        unsigned short t2 = f2bf(r1 - bf2f(t1));
        wsu[2 * WS_WBF + i] = (s == 0) ? t0 : ((s == 1) ? t1 : t2);
    }
}

// ---------------------------------------------------------------------------
// Kernel 2: fused features + BiLSTM (3-term split-bf16 MFMA) + emissions.
// R27 = R23 (the verified 623 us best) with ONE isolated change: s_setprio
// REMOVED. T5 evidence (learn_hip m190/m218b): setprio only pays when a
// phase-split gives waves different roles; in a barrier-locked 2-waves/SIMD
// schedule both co-resident waves sit in the same phase, and m190 measured
// setprio at -1.5% on exactly this lockstep regime. R23 inherited it
// un-A/B'd from R21. Everything else is byte-for-byte R23:
//  * W ping-pong wX/wY[2][3]: first half MFMAs wX=(nt01,Ks) while loading
//    wY<-(nt23,Ks); second half MFMAs wY while loading wX<-(nt01,Ks+1).
//  * A-plane double buffer (ah/al/am): next round's 6 ds_reads issued
//    before the current 24 MFMAs.
//  * 2-site FEAT stagger (even waves Ks=4, odd Ks=8), emissions + gates
//    post-loop, cross-barrier Ks0 W prefetch.
// Numerics bitwise identical to R9-R26. LDS 157,408 B (1 block/CU),
// 8 waves, 2/SIMD, VGPR ~120 (no spill).
// ---------------------------------------------------------------------------
__global__ __launch_bounds__(512, 2)
void lstm_kernel(const int* __restrict__ x, float* __restrict__ ws)
{
    __shared__ unsigned short Fh[2][NB * FSTR], Fl[2][NB * FSTR], Fm[2][NB * FSTR];
    __shared__ unsigned short Hh[2][NB * HSTR], Hl[2][NB * HSTR], Hm[2][NB * HSTR];
    __shared__ float Pp_s[3600];
    __shared__ float Wfc_s[384];
    __shared__ float biasC_s[40];

    const int tid = threadIdx.x;
    const int d   = blockIdx.x & 1;
    const int b0  = (blockIdx.x >> 1) * NB;

    const unsigned short* __restrict__ Wb =
        (const unsigned short*)ws + 2 * WS_WBF + d * (512 * CW);
    float* emis = ws + WS_EMIS + d * (BB * LL * TT);

    for (int i = tid; i < 3600; i += NT_) Pp_s[i] = ws[WS_P + i];
    for (int i = tid; i < 384;  i += NT_) Wfc_s[i] = ws[WS_WFC + d * 384 + i];
    for (int i = tid; i < 40;   i += NT_) biasC_s[i] = ws[WS_BC + i];
    // zero F (both buffers; covers K pads) and H (both buffers; h_{-1}=0)
    for (int i = tid; i < NB * FSTR; i += NT_) {
        ((unsigned*)Fh)[i] = 0u; ((unsigned*)Fl)[i] = 0u; ((unsigned*)Fm)[i] = 0u;
    }
    for (int i = tid; i < NB * HSTR; i += NT_) {
        ((unsigned*)Hh)[i] = 0u; ((unsigned*)Hl)[i] = 0u; ((unsigned*)Hm)[i] = 0u;
    }

    const int lane = tid & 63;
    const int wv   = tid >> 6;          // 0..7: N-tile group (gate-cols 64*wv..)
    const int quad = lane >> 4;
    const int ml   = lane & 15;

    // 4 W base pointers, one per nt; all further offsets are immediates.
    const unsigned short* __restrict__ Wn[4] = {
        Wb + (wv * 64 +  0 + ml) * CW + quad * 8,
        Wb + (wv * 64 + 16 + ml) * CW + quad * 8,
        Wb + (wv * 64 + 32 + ml) * CW + quad * 8,
        Wb + (wv * 64 + 48 + ml) * CW + quad * 8
    };

    // this lane's units (one per nt) and their gate biases
    const float* bgp = ws + WS_BG + d * 512;
    int   un[4];
    float bIv[4], bFv[4], bGv[4], bOv[4];
    #pragma unroll
    for (int nt = 0; nt < 4; ++nt) {
        int u = wv * 16 + nt * 4 + quad;
        un[nt]  = u;
        bIv[nt] = bgp[u];
        bFv[nt] = bgp[128 + u];
        bGv[nt] = bgp[256 + u];
        bOv[nt] = bgp[384 + u];
    }

    float cst[2][4];
    #pragma unroll
    for (int mt = 0; mt < 2; ++mt)
        #pragma unroll
        for (int nt = 0; nt < 4; ++nt) cst[mt][nt] = 0.f;

    __syncthreads();

    // ---- one feature item (batch bb, channel c) for seq position l ----
#define FEAT_ONE(LPOS, BUF, P)                                                 \
    {                                                                          \
        int bb = (P) / CC, c = (P) % CC;                                       \
        const int* tok = x + (((b0 + bb) * LL) + (LPOS)) * WW;                 \
        int t0 = tok[0], t1 = tok[1], t2 = tok[2], t3 = tok[3], t4 = tok[4];   \
        float bc = biasC_s[c];                                                 \
        float a0 = bc + Pp_s[(30 + t0) * 40 + c] + Pp_s[(60 + t1) * 40 + c];   \
        float a1 = bc + Pp_s[t0 * 40 + c] + Pp_s[(30 + t1) * 40 + c] + Pp_s[(60 + t2) * 40 + c]; \
        float a2 = bc + Pp_s[t1 * 40 + c] + Pp_s[(30 + t2) * 40 + c] + Pp_s[(60 + t3) * 40 + c]; \
        float a3 = bc + Pp_s[t2 * 40 + c] + Pp_s[(30 + t3) * 40 + c] + Pp_s[(60 + t4) * 40 + c]; \
        float a4 = bc + Pp_s[t3 * 40 + c] + Pp_s[(30 + t4) * 40 + c];          \
        a0 = fmaxf(a0, 0.f); a1 = fmaxf(a1, 0.f); a2 = fmaxf(a2, 0.f);         \
        a3 = fmaxf(a3, 0.f); a4 = fmaxf(a4, 0.f);                              \
        float f[5];                                                            \
        f[0] = fmaxf(a0, a1);                                                  \
        f[1] = fmaxf(fmaxf(a0, a1), a2);                                       \
        f[2] = fmaxf(fmaxf(a1, a2), a3);                                       \
        f[3] = fmaxf(fmaxf(a2, a3), a4);                                       \
        f[4] = fmaxf(a3, a4);                                                  \
        int base = bb * FSTR + c * 5;                                          \
        _Pragma("unroll")                                                      \
        for (int j = 0; j < 5; ++j) {                                          \
            unsigned short h0 = f2bf(f[j]);                                    \
            float r1 = f[j] - bf2f(h0);                                        \
            unsigned short h1 = f2bf(r1);                                      \
            unsigned short h2 = f2bf(r1 - bf2f(h1));                           \
            Fh[BUF][base + j] = h0;                                            \
            Fl[BUF][base + j] = h1;                                            \
            Fm[BUF][base + j] = h2;                                            \
        }                                                                      \
    }

    // all feature items for this thread: 1280 items over 512 threads.
#define FEAT_ALL(LPOS, BUF)                                                    \
    {                                                                          \
        FEAT_ONE(LPOS, BUF, tid)                                               \
        FEAT_ONE(LPOS, BUF, tid + 512)                                         \
        if (tid >= 256) FEAT_ONE(LPOS, BUF, tid + 768)                         \
    }

    // emissions for one seq position from H buffer HB (threads 0..191)
#define EMIS_BODY(LPOS, HB)                                                    \
    {                                                                          \
        int bb = tid / 6, r6 = tid % 6, t = r6 >> 1, seg = r6 & 1;             \
        int hoff = bb * HSTR + seg * 64;                                       \
        const float* wfc = &Wfc_s[t * 128 + seg * 64];                         \
        float s = 0.f;                                                         \
        _Pragma("unroll")                                                      \
        for (int i = 0; i < 8; ++i) {                                          \
            u16x8 v0 = *(const u16x8*)&Hh[HB][hoff + i * 8];                   \
            u16x8 v1 = *(const u16x8*)&Hl[HB][hoff + i * 8];                   \
            u16x8 v2 = *(const u16x8*)&Hm[HB][hoff + i * 8];                   \
            _Pragma("unroll")                                                  \
            for (int j = 0; j < 8; ++j) {                                      \
                float h = bf2f(v0[j]) + bf2f(v1[j]) + bf2f(v2[j]);             \
                s += h * wfc[i * 8 + j];                                       \
            }                                                                  \
        }                                                                      \
        s += __shfl_xor(s, 1);                                                 \
        if (seg == 0)                                                          \
            emis[(((b0 + bb) * LL) + (LPOS)) * TT + t] = s;                    \
    }

    // prologue: features for step 0
    {
        const int l0 = d ? (LL - 1) : 0;
        FEAT_ALL(l0, 0)
    }

#define WLOAD(B, P, KS)                                                        \
        {                                                                      \
            B[0] = *(const bf16x8*)((P) + (KS) * 96);                          \
            B[1] = *(const bf16x8*)((P) + (KS) * 96 + 32);                     \
            B[2] = *(const bf16x8*)((P) + (KS) * 96 + 64);                     \
        }
    // A-plane loads (all 3 split terms, both m-tiles) for round KS -> buf BUF
#define LDA(BUF, KS)                                                           \
        {                                                                      \
            if ((KS) < 7) {                                                    \
                const int ko_ = (KS) * 32 + quad * 8;                          \
                ah[BUF][0] = *(const bf16x8*)&Fh[fb][ml * FSTR + ko_];         \
                al[BUF][0] = *(const bf16x8*)&Fl[fb][ml * FSTR + ko_];         \
                am[BUF][0] = *(const bf16x8*)&Fm[fb][ml * FSTR + ko_];         \
                ah[BUF][1] = *(const bf16x8*)&Fh[fb][(16 + ml) * FSTR + ko_];  \
                al[BUF][1] = *(const bf16x8*)&Fl[fb][(16 + ml) * FSTR + ko_];  \
                am[BUF][1] = *(const bf16x8*)&Fm[fb][(16 + ml) * FSTR + ko_];  \
            } else {                                                           \
                const int ko_ = ((KS) - 7) * 32 + quad * 8;                    \
                ah[BUF][0] = *(const bf16x8*)&Hh[hr][ml * HSTR + ko_];         \
                al[BUF][0] = *(const bf16x8*)&Hl[hr][ml * HSTR + ko_];         \
                am[BUF][0] = *(const bf16x8*)&Hm[hr][ml * HSTR + ko_];         \
                ah[BUF][1] = *(const bf16x8*)&Hh[hr][(16 + ml) * HSTR + ko_];  \
                al[BUF][1] = *(const bf16x8*)&Hl[hr][(16 + ml) * HSTR + ko_];  \
                am[BUF][1] = *(const bf16x8*)&Hm[hr][(16 + ml) * HSTR + ko_];  \
            }                                                                  \
        }
    // D = W' * A' — same 6 products, same order per acc chain as R9-R26
#define GEMM6X(B, CB, NT)                                                      \
        {                                                                      \
            acc[0][NT] = __builtin_amdgcn_mfma_f32_16x16x32_bf16(B[0], ah[CB][0], acc[0][NT], 0, 0, 0); \
            acc[0][NT] = __builtin_amdgcn_mfma_f32_16x16x32_bf16(B[0], al[CB][0], acc[0][NT], 0, 0, 0); \
            acc[0][NT] = __builtin_amdgcn_mfma_f32_16x16x32_bf16(B[1], ah[CB][0], acc[0][NT], 0, 0, 0); \
            acc[0][NT] = __builtin_amdgcn_mfma_f32_16x16x32_bf16(B[1], al[CB][0], acc[0][NT], 0, 0, 0); \
            acc[0][NT] = __builtin_amdgcn_mfma_f32_16x16x32_bf16(B[2], ah[CB][0], acc[0][NT], 0, 0, 0); \
            acc[0][NT] = __builtin_amdgcn_mfma_f32_16x16x32_bf16(B[0], am[CB][0], acc[0][NT], 0, 0, 0); \
            acc[1][NT] = __builtin_amdgcn_mfma_f32_16x16x32_bf16(B[0], ah[CB][1], acc[1][NT], 0, 0, 0); \
            acc[1][NT] = __builtin_amdgcn_mfma_f32_16x16x32_bf16(B[0], al[CB][1], acc[1][NT], 0, 0, 0); \
            acc[1][NT] = __builtin_amdgcn_mfma_f32_16x16x32_bf16(B[1], ah[CB][1], acc[1][NT], 0, 0, 0); \
            acc[1][NT] = __builtin_amdgcn_mfma_f32_16x16x32_bf16(B[1], al[CB][1], acc[1][NT], 0, 0, 0); \
            acc[1][NT] = __builtin_amdgcn_mfma_f32_16x16x32_bf16(B[2], ah[CB][1], acc[1][NT], 0, 0, 0); \
            acc[1][NT] = __builtin_amdgcn_mfma_f32_16x16x32_bf16(B[0], am[CB][1], acc[1][NT], 0, 0, 0); \
        }

    // W ping-pong buffers live across the whole step loop; prefetch the
    // first half (nt01, Ks=0) now — stays in flight across the barrier.
    bf16x8 wX[2][3], wY[2][3];
    WLOAD(wX[0], Wn[0], 0)
    WLOAD(wX[1], Wn[1], 0)

    __syncthreads();   // F(0) + LDS init visible

    for (int step = 0; step < LL; ++step) {
        const int fb = step & 1;
        const int hw = step & 1;        // h_step is written here
        const int hr = hw ^ 1;          // h_{step-1} lives here (zeros at step 0)

        f32x4 acc[2][4];
        #pragma unroll
        for (int mt = 0; mt < 2; ++mt)
            #pragma unroll
            for (int nt = 0; nt < 4; ++nt)
                acc[mt][nt] = (f32x4){0.f, 0.f, 0.f, 0.f};

        {
            // prime the A pipeline: round 0's planes
            bf16x8 ah[2][2], al[2][2], am[2][2];
            LDA(0, 0)

            #pragma unroll
            for (int Ks = 0; Ks < 11; ++Ks) {
                const int cb = Ks & 1, nb = cb ^ 1;

                // ---- first half: MFMA wX=(nt01,Ks); load wY<-(nt23,Ks) ----
                WLOAD(wY[0], Wn[2], Ks)
                WLOAD(wY[1], Wn[3], Ks)
                // next-round A planes (6 ds_reads; drain under the MFMAs)
                if (Ks < 10) LDA(nb, Ks + 1)

                GEMM6X(wX[0], cb, 0)
                GEMM6X(wX[1], cb, 1)

                // ---- second half: MFMA wY=(nt23,Ks); load wX<-(nt01,Ks+1) --
                if (Ks < 10) {
                    WLOAD(wX[0], Wn[0], Ks + 1)
                    WLOAD(wX[1], Wn[1], Ks + 1)
                }
                GEMM6X(wY[0], cb, 2)
                GEMM6X(wY[1], cb, 3)

                // Two-point wave-staggered features(t+1) in the MFMA shadow:
                // even waves at Ks=4, odd waves at Ks=8. Writes F[fb^1],
                // disjoint from this step's F[fb] reads.
                if (Ks == 4 && step + 1 < LL && (wv & 1) == 0) {
                    const int lnext = d ? (LL - 2 - step) : (step + 1);
                    FEAT_ALL(lnext, fb ^ 1)
                }
                if (Ks == 8 && step + 1 < LL && (wv & 1) == 1) {
                    const int lnext = d ? (LL - 2 - step) : (step + 1);
                    FEAT_ALL(lnext, fb ^ 1)
                }
            }
        }

        // emissions for step-1 (reads H[hr] = h_{step-1}; gates write H[hw])
        if (step > 0 && tid < 192) {
            const int lprev = d ? (LL - step) : (step - 1);
            EMIS_BODY(lprev, hr)
        }

        // gates in-register -> h into H[hw] (nobody reads H[hw] this step)
        #pragma unroll
        for (int mt = 0; mt < 2; ++mt) {
            #pragma unroll
            for (int nt = 0; nt < 4; ++nt) {
                float zi = acc[mt][nt][0] + bIv[nt];
                float zf = acc[mt][nt][1] + bFv[nt];
                float zg = acc[mt][nt][2] + bGv[nt];
                float zo = acc[mt][nt][3] + bOv[nt];
                float cn = sigm(zf) * cst[mt][nt] + sigm(zi) * tanh_fast(zg);
                cst[mt][nt] = cn;
                float h = sigm(zo) * tanh_fast(cn);
                unsigned short h0 = f2bf(h);
                float r1 = h - bf2f(h0);
                unsigned short h1 = f2bf(r1);
                unsigned short h2 = f2bf(r1 - bf2f(h1));
                int idx = (mt * 16 + ml) * HSTR + un[nt];
                Hh[hw][idx] = h0;
                Hl[hw][idx] = h1;
                Hm[hw][idx] = h2;
            }
        }

        // prefetch next step's first half (nt01, Ks=0); stays in flight
        // across the barrier (wX was fully consumed by round 10's first half).
        if (step + 1 < LL) {
            WLOAD(wX[0], Wn[0], 0)
            WLOAD(wX[1], Wn[1], 0)
        }

        __syncthreads();   // h_step + F(t+1) visible; H[hr]/F[fb] free for reuse
    }
#undef GEMM6X
#undef LDA
#undef WLOAD

    // epilogue: emissions for the last step (h_{LL-1} lives in H[(LL-1)&1])
    if (tid < 192) {
        const int llast = d ? 0 : (LL - 1);
        const int hl_ = (LL - 1) & 1;
        EMIS_BODY(llast, hl_)
    }
#undef EMIS_BODY
#undef FEAT_ALL
#undef FEAT_ONE
}

// ---------------------------------------------------------------------------
// Kernel 3: Viterbi decode. One thread per batch row. (unchanged)
// ---------------------------------------------------------------------------
__global__ void viterbi_kernel(const int* __restrict__ x, const float* __restrict__ ws,
                               const float* __restrict__ trans,
                               const float* __restrict__ start_t,
                               const float* __restrict__ end_t,
                               float* __restrict__ out)
{
    int b = blockIdx.x * blockDim.x + threadIdx.x;
    if (b >= BB) return;
    const float* eF = ws + WS_EMIS;
    const float* eB = ws + WS_EMIS + BB * LL * TT;
    const float eb0 = ws[WS_EB + 0], eb1 = ws[WS_EB + 1], eb2 = ws[WS_EB + 2];
    float tr[9];
    #pragma unroll
    for (int i = 0; i < 9; ++i) tr[i] = trans[i];

    int base = b * LL * TT;
    float s0 = start_t[0] + eF[base + 0] + eB[base + 0] + eb0;
    float s1 = start_t[1] + eF[base + 1] + eB[base + 1] + eb1;
    float s2 = start_t[2] + eF[base + 2] + eB[base + 2] + eb2;

    unsigned hist[LL - 1];
    unsigned maskbits = 0;

    #pragma unroll
    for (int l = 1; l < LL; ++l) {
        bool m = x[(b * LL + l) * WW + 2] > 0;
        if (m) maskbits |= (1u << l);
        int idx = base + l * TT;
        float e0 = eF[idx + 0] + eB[idx + 0] + eb0;
        float e1 = eF[idx + 1] + eB[idx + 1] + eb1;
        float e2 = eF[idx + 2] + eB[idx + 2] + eb2;

        float ns[3]; int pt[3];
        #pragma unroll
        for (int nt = 0; nt < 3; ++nt) {
            float c0 = s0 + tr[0 * 3 + nt];
            float c1 = s1 + tr[1 * 3 + nt];
            float c2 = s2 + tr[2 * 3 + nt];
            int p = 0; float bc = c0;
            if (c1 > bc) { bc = c1; p = 1; }   // strict '>': first-index argmax
            if (c2 > bc) { bc = c2; p = 2; }
            ns[nt] = bc; pt[nt] = p;
        }
        ns[0] += e0; ns[1] += e1; ns[2] += e2;
        hist[l - 1] = (unsigned)pt[0] | ((unsigned)pt[1] << 2) | ((unsigned)pt[2] << 4);
        if (m) { s0 = ns[0]; s1 = ns[1]; s2 = ns[2]; }
    }
    s0 += end_t[0]; s1 += end_t[1]; s2 += end_t[2];
    float best = s0; int last = 0;
    if (s1 > best) { best = s1; last = 1; }
    if (s2 > best) { best = s2; last = 2; }

    out[b] = best;
    float* tags = out + BB + b * LL;
    int tag = last;
    tags[LL - 1] = (float)last;
    #pragma unroll
    for (int l = LL - 1; l >= 1; --l) {
        int prev = (int)((hist[l - 1] >> (2 * tag)) & 3u);
        if (maskbits & (1u << l)) tag = prev;
        tags[l - 1] = (float)tag;
    }
}

// ---------------------------------------------------------------------------
extern "C" void kernel_launch(void* const* d_in, const int* in_sizes, int n_in,
                              void* d_out, int out_size, void* d_ws, size_t ws_size,
                              hipStream_t stream)
{
    const int*   x      = (const int*)  d_in[0];
    const float* emb    = (const float*)d_in[1];
    const float* conv_w = (const float*)d_in[2];
    const float* conv_b = (const float*)d_in[3];
    const float* bn1_g  = (const float*)d_in[4];
    const float* bn1_b  = (const float*)d_in[5];
    const float* bn1_m  = (const float*)d_in[6];
    const float* bn1_v  = (const float*)d_in[7];
    const float* w_ih_f = (const float*)d_in[8];
    const float* w_hh_f = (const float*)d_in[9];
    const float* b_f    = (const float*)d_in[10];
    const float* w_ih_b = (const float*)d_in[11];
    const float* w_hh_b = (const float*)d_in[12];
    const float* b_b    = (const float*)d_in[13];
    const float* bn2_g  = (const float*)d_in[14];
    const float* bn2_b  = (const float*)d_in[15];
    const float* bn2_m  = (const float*)d_in[16];
    const float* bn2_v  = (const float*)d_in[17];
    const float* fc_w   = (const float*)d_in[18];
    const float* fc_b   = (const float*)d_in[19];
    const float* trans  = (const float*)d_in[20];
    const float* start_t= (const float*)d_in[21];
    const float* end_t  = (const float*)d_in[22];

    float* ws  = (float*)d_ws;
    float* out = (float*)d_out;

    prep_kernel<<<256, 256, 0, stream>>>(emb, conv_w, conv_b,
                                         bn1_g, bn1_b, bn1_m, bn1_v,
                                         w_ih_f, w_hh_f, b_f,
                                         w_ih_b, w_hh_b, b_b,
                                         bn2_g, bn2_b, bn2_m, bn2_v,
                                         fc_w, fc_b, ws);
    lstm_kernel<<<256, 512, 0, stream>>>(x, ws);
    viterbi_kernel<<<16, 256, 0, stream>>>(x, ws, trans, start_t, end_t, out);
}

// Round 12
// 699.329 us; speedup vs baseline: 1.0877x; 1.0436x over previous
//
#include <hip/hip_runtime.h>
#include <math.h>

// Problem constants
#define BB    4096   // batch
#define LL    30     // seq len
#define WW    5      // window
#define CC    40     // conv channels
#define HH    128    // lstm units
#define TT    3      // crf tags
#define KA    328    // 200 (features) + 128 (h)
#define NB    32     // batch rows per LSTM block
#define NT_   512    // threads per block (8 waves -> 2 waves/SIMD -> no spill)
#define FSTR  232    // F row stride (u16): 7 K-chunks = 224 cols (200 real + 24 pad)
#define HSTR  136    // H row stride (u16): 128 cols + pad (16B-aligned rows)
#define CW    1056   // per-column W footprint in ushorts: 11 Ks * 3 s * 32 k
#define VROWS 64     // viterbi rows per block (R28: LDS-staged coalesced)

// Workspace layout (in floats)
#define WS_P    0                         // P'[3][30][40] conv collapsed + bn1 folded
#define WS_BC   3600                      // biasC[40]
#define WS_BG   3648                      // biasG[2][512]
#define WS_WFC  4672                      // Wfc[2][3][128]  (fc folded with bn2)
#define WS_EB   5440                      // ebias[3]
#define WS_WBF  5504                      // bf16 W [d][n][Ks][s][32]: 540672 floats
#define WS_EMIS (5504 + 540672)           // emis[2][B][L][3] partial emissions

typedef __bf16 bf16x8 __attribute__((ext_vector_type(8)));
typedef float  f32x4  __attribute__((ext_vector_type(4)));
typedef unsigned short u16x8 __attribute__((ext_vector_type(8)));

__device__ __forceinline__ float sigm(float x) {
    return __builtin_amdgcn_rcpf(1.0f + __expf(-x));
}
__device__ __forceinline__ float tanh_fast(float x) {
    return 2.0f * __builtin_amdgcn_rcpf(1.0f + __expf(-2.0f * x)) - 1.0f;
}
// bf16 round-to-nearest-even helpers
__device__ __forceinline__ unsigned short f2bf(float f) {
    unsigned u = __builtin_bit_cast(unsigned, f);
    return (unsigned short)((u + 0x7FFFu + ((u >> 16) & 1u)) >> 16);
}
__device__ __forceinline__ float bf2f(unsigned short h) {
    unsigned u = ((unsigned)h) << 16;
    return __builtin_bit_cast(float, u);
}

// ---------------------------------------------------------------------------
// Kernel 1: fold BN1 into conv tables, 3-term split-bf16 repack of LSTM
// weights ([d][n][Ks][s][32]), fold BN2 into FC. (unchanged)
// ---------------------------------------------------------------------------
__global__ void prep_kernel(const float* __restrict__ emb, const float* __restrict__ conv_w,
                            const float* __restrict__ conv_b,
                            const float* __restrict__ bn1_g, const float* __restrict__ bn1_b,
                            const float* __restrict__ bn1_m, const float* __restrict__ bn1_v,
                            const float* __restrict__ w_ih_f, const float* __restrict__ w_hh_f,
                            const float* __restrict__ b_f,
                            const float* __restrict__ w_ih_b, const float* __restrict__ w_hh_b,
                            const float* __restrict__ b_b,
                            const float* __restrict__ bn2_g, const float* __restrict__ bn2_b,
                            const float* __restrict__ bn2_m, const float* __restrict__ bn2_v,
                            const float* __restrict__ fc_w, const float* __restrict__ fc_b,
                            float* __restrict__ ws)
{
    const int gid = blockIdx.x * blockDim.x + threadIdx.x;
    const int gsz = gridDim.x * blockDim.x;

    for (int idx = gid; idx < 3600; idx += gsz) {
        int k = idx / 1200, rem = idx % 1200, a = rem / 40, c = rem % 40;
        float s1 = bn1_g[c] / sqrtf(bn1_v[c] + 1e-5f);
        float acc = 0.f;
        for (int e = 0; e < 128; ++e)
            acc += emb[a * 128 + e] * conv_w[(c * 128 + e) * 3 + k];
        ws[WS_P + idx] = acc * s1;
    }
    for (int c = gid; c < CC; c += gsz) {
        float s1 = bn1_g[c] / sqrtf(bn1_v[c] + 1e-5f);
        ws[WS_BC + c] = (conv_b[c] - bn1_m[c]) * s1 + bn1_b[c];
    }
    for (int i = gid; i < 1024; i += gsz) {
        int d = i >> 9, g = i & 511;
        ws[WS_BG + i] = d ? b_b[g] : b_f[g];
    }
    for (int i = gid; i < 768; i += gsz) {
        int d = i / 384, r = i % 384, t = r / 128, u = r % 128;
        int j = d * 128 + u;
        float s2 = bn2_g[j] / sqrtf(bn2_v[j] + 1e-5f);
        ws[WS_WFC + i] = fc_w[t * 256 + j] * s2;
    }
    for (int t = gid; t < TT; t += gsz) {
        float acc = fc_b[t];
        for (int j = 0; j < 256; ++j) {
            float s2 = bn2_g[j] / sqrtf(bn2_v[j] + 1e-5f);
            acc += fc_w[t * 256 + j] * (bn2_b[j] - bn2_m[j] * s2);
        }
        ws[WS_EB + t] = acc;
    }
    // Wbf[d][n][Ks][s][32]: n = 4u+g; per column all Ks/s chunks contiguous.
    unsigned short* wsu = (unsigned short*)ws;
    for (int i = gid; i < 2 * 512 * CW; i += gsz) {
        int d = i / (512 * CW), r = i % (512 * CW);
        int n = r / CW, q = r % CW;
        int Ks = q / 96, t = q % 96, s = t / 32, k32 = t % 32;
        int k = Ks * 32 + k32;
        int u = n >> 2, g = n & 3, row = g * 128 + u;
        const float* wih = d ? w_ih_b : w_ih_f;
        const float* whh = d ? w_hh_b : w_hh_f;
        float w = (k < 200) ? wih[row * 200 + k]
                            : ((k >= 224) ? whh[row * 128 + (k - 224)] : 0.f);
        unsigned short t0 = f2bf(w);
        float r1 = w - bf2f(t0);
        unsigned short t1 = f2bf(r1);
        unsigned short t2 = f2bf(r1 - bf2f(t1));
        wsu[2 * WS_WBF + i] = (s == 0) ? t0 : ((s == 1) ? t1 : t2);
    }
}

// ---------------------------------------------------------------------------
// Kernel 2: fused features + BiLSTM (3-term split-bf16 MFMA) + emissions.
// R28 = R23 restored byte-for-byte (623 us verified best). The R27 A/B
// showed setprio is load-bearing here (+6%: removing it cost 623->663,
// MfmaUtil 38.4->35.4): the FEAT stagger at Ks=4/8 gives co-resident waves
// role diversity, which is T5's prerequisite — m190's lockstep null does
// not transfer. Schedule ledger now exhausted: R18/R20/R21/R22/R26 spilled
// (register pool 2048/CU: >~120 live regs/wave at any wave count the
// allocator accepts), R24/R25 null-to-negative, R27 regressed.
//  * W ping-pong wX/wY[2][3]; A-plane double buffer; 2-site FEAT stagger
//    (even waves Ks=4, odd Ks=8); emissions + gates post-loop;
//    cross-barrier Ks0 W prefetch; setprio(1/0) around MFMA clusters.
// Numerics bitwise identical to R9-R27. LDS 157,408 B (1 block/CU),
// 8 waves, 2/SIMD, VGPR ~120 (no spill).
// ---------------------------------------------------------------------------
__global__ __launch_bounds__(512, 2)
void lstm_kernel(const int* __restrict__ x, float* __restrict__ ws)
{
    __shared__ unsigned short Fh[2][NB * FSTR], Fl[2][NB * FSTR], Fm[2][NB * FSTR];
    __shared__ unsigned short Hh[2][NB * HSTR], Hl[2][NB * HSTR], Hm[2][NB * HSTR];
    __shared__ float Pp_s[3600];
    __shared__ float Wfc_s[384];
    __shared__ float biasC_s[40];

    const int tid = threadIdx.x;
    const int d   = blockIdx.x & 1;
    const int b0  = (blockIdx.x >> 1) * NB;

    const unsigned short* __restrict__ Wb =
        (const unsigned short*)ws + 2 * WS_WBF + d * (512 * CW);
    float* emis = ws + WS_EMIS + d * (BB * LL * TT);

    for (int i = tid; i < 3600; i += NT_) Pp_s[i] = ws[WS_P + i];
    for (int i = tid; i < 384;  i += NT_) Wfc_s[i] = ws[WS_WFC + d * 384 + i];
    for (int i = tid; i < 40;   i += NT_) biasC_s[i] = ws[WS_BC + i];
    // zero F (both buffers; covers K pads) and H (both buffers; h_{-1}=0)
    for (int i = tid; i < NB * FSTR; i += NT_) {
        ((unsigned*)Fh)[i] = 0u; ((unsigned*)Fl)[i] = 0u; ((unsigned*)Fm)[i] = 0u;
    }
    for (int i = tid; i < NB * HSTR; i += NT_) {
        ((unsigned*)Hh)[i] = 0u; ((unsigned*)Hl)[i] = 0u; ((unsigned*)Hm)[i] = 0u;
    }

    const int lane = tid & 63;
    const int wv   = tid >> 6;          // 0..7: N-tile group (gate-cols 64*wv..)
    const int quad = lane >> 4;
    const int ml   = lane & 15;

    // 4 W base pointers, one per nt; all further offsets are immediates.
    const unsigned short* __restrict__ Wn[4] = {
        Wb + (wv * 64 +  0 + ml) * CW + quad * 8,
        Wb + (wv * 64 + 16 + ml) * CW + quad * 8,
        Wb + (wv * 64 + 32 + ml) * CW + quad * 8,
        Wb + (wv * 64 + 48 + ml) * CW + quad * 8
    };

    // this lane's units (one per nt) and their gate biases
    const float* bgp = ws + WS_BG + d * 512;
    int   un[4];
    float bIv[4], bFv[4], bGv[4], bOv[4];
    #pragma unroll
    for (int nt = 0; nt < 4; ++nt) {
        int u = wv * 16 + nt * 4 + quad;
        un[nt]  = u;
        bIv[nt] = bgp[u];
        bFv[nt] = bgp[128 + u];
        bGv[nt] = bgp[256 + u];
        bOv[nt] = bgp[384 + u];
    }

    float cst[2][4];
    #pragma unroll
    for (int mt = 0; mt < 2; ++mt)
        #pragma unroll
        for (int nt = 0; nt < 4; ++nt) cst[mt][nt] = 0.f;

    __syncthreads();

    // ---- one feature item (batch bb, channel c) for seq position l ----
#define FEAT_ONE(LPOS, BUF, P)                                                 \
    {                                                                          \
        int bb = (P) / CC, c = (P) % CC;                                       \
        const int* tok = x + (((b0 + bb) * LL) + (LPOS)) * WW;                 \
        int t0 = tok[0], t1 = tok[1], t2 = tok[2], t3 = tok[3], t4 = tok[4];   \
        float bc = biasC_s[c];                                                 \
        float a0 = bc + Pp_s[(30 + t0) * 40 + c] + Pp_s[(60 + t1) * 40 + c];   \
        float a1 = bc + Pp_s[t0 * 40 + c] + Pp_s[(30 + t1) * 40 + c] + Pp_s[(60 + t2) * 40 + c]; \
        float a2 = bc + Pp_s[t1 * 40 + c] + Pp_s[(30 + t2) * 40 + c] + Pp_s[(60 + t3) * 40 + c]; \
        float a3 = bc + Pp_s[t2 * 40 + c] + Pp_s[(30 + t3) * 40 + c] + Pp_s[(60 + t4) * 40 + c]; \
        float a4 = bc + Pp_s[t3 * 40 + c] + Pp_s[(30 + t4) * 40 + c];          \
        a0 = fmaxf(a0, 0.f); a1 = fmaxf(a1, 0.f); a2 = fmaxf(a2, 0.f);         \
        a3 = fmaxf(a3, 0.f); a4 = fmaxf(a4, 0.f);                              \
        float f[5];                                                            \
        f[0] = fmaxf(a0, a1);                                                  \
        f[1] = fmaxf(fmaxf(a0, a1), a2);                                       \
        f[2] = fmaxf(fmaxf(a1, a2), a3);                                       \
        f[3] = fmaxf(fmaxf(a2, a3), a4);                                       \
        f[4] = fmaxf(a3, a4);                                                  \
        int base = bb * FSTR + c * 5;                                          \
        _Pragma("unroll")                                                      \
        for (int j = 0; j < 5; ++j) {                                          \
            unsigned short h0 = f2bf(f[j]);                                    \
            float r1 = f[j] - bf2f(h0);                                        \
            unsigned short h1 = f2bf(r1);                                      \
            unsigned short h2 = f2bf(r1 - bf2f(h1));                           \
            Fh[BUF][base + j] = h0;                                            \
            Fl[BUF][base + j] = h1;                                            \
            Fm[BUF][base + j] = h2;                                            \
        }                                                                      \
    }

    // all feature items for this thread: 1280 items over 512 threads.
#define FEAT_ALL(LPOS, BUF)                                                    \
    {                                                                          \
        FEAT_ONE(LPOS, BUF, tid)                                               \
        FEAT_ONE(LPOS, BUF, tid + 512)                                         \
        if (tid >= 256) FEAT_ONE(LPOS, BUF, tid + 768)                         \
    }

    // emissions for one seq position from H buffer HB (threads 0..191)
#define EMIS_BODY(LPOS, HB)                                                    \
    {                                                                          \
        int bb = tid / 6, r6 = tid % 6, t = r6 >> 1, seg = r6 & 1;             \
        int hoff = bb * HSTR + seg * 64;                                       \
        const float* wfc = &Wfc_s[t * 128 + seg * 64];                         \
        float s = 0.f;                                                         \
        _Pragma("unroll")                                                      \
        for (int i = 0; i < 8; ++i) {                                          \
            u16x8 v0 = *(const u16x8*)&Hh[HB][hoff + i * 8];                   \
            u16x8 v1 = *(const u16x8*)&Hl[HB][hoff + i * 8];                   \
            u16x8 v2 = *(const u16x8*)&Hm[HB][hoff + i * 8];                   \
            _Pragma("unroll")                                                  \
            for (int j = 0; j < 8; ++j) {                                      \
                float h = bf2f(v0[j]) + bf2f(v1[j]) + bf2f(v2[j]);             \
                s += h * wfc[i * 8 + j];                                       \
            }                                                                  \
        }                                                                      \
        s += __shfl_xor(s, 1);                                                 \
        if (seg == 0)                                                          \
            emis[(((b0 + bb) * LL) + (LPOS)) * TT + t] = s;                    \
    }

    // prologue: features for step 0
    {
        const int l0 = d ? (LL - 1) : 0;
        FEAT_ALL(l0, 0)
    }

#define WLOAD(B, P, KS)                                                        \
        {                                                                      \
            B[0] = *(const bf16x8*)((P) + (KS) * 96);                          \
            B[1] = *(const bf16x8*)((P) + (KS) * 96 + 32);                     \
            B[2] = *(const bf16x8*)((P) + (KS) * 96 + 64);                     \
        }
    // A-plane loads (all 3 split terms, both m-tiles) for round KS -> buf BUF
#define LDA(BUF, KS)                                                           \
        {                                                                      \
            if ((KS) < 7) {                                                    \
                const int ko_ = (KS) * 32 + quad * 8;                          \
                ah[BUF][0] = *(const bf16x8*)&Fh[fb][ml * FSTR + ko_];         \
                al[BUF][0] = *(const bf16x8*)&Fl[fb][ml * FSTR + ko_];         \
                am[BUF][0] = *(const bf16x8*)&Fm[fb][ml * FSTR + ko_];         \
                ah[BUF][1] = *(const bf16x8*)&Fh[fb][(16 + ml) * FSTR + ko_];  \
                al[BUF][1] = *(const bf16x8*)&Fl[fb][(16 + ml) * FSTR + ko_];  \
                am[BUF][1] = *(const bf16x8*)&Fm[fb][(16 + ml) * FSTR + ko_];  \
            } else {                                                           \
                const int ko_ = ((KS) - 7) * 32 + quad * 8;                    \
                ah[BUF][0] = *(const bf16x8*)&Hh[hr][ml * HSTR + ko_];         \
                al[BUF][0] = *(const bf16x8*)&Hl[hr][ml * HSTR + ko_];         \
                am[BUF][0] = *(const bf16x8*)&Hm[hr][ml * HSTR + ko_];         \
                ah[BUF][1] = *(const bf16x8*)&Hh[hr][(16 + ml) * HSTR + ko_];  \
                al[BUF][1] = *(const bf16x8*)&Hl[hr][(16 + ml) * HSTR + ko_];  \
                am[BUF][1] = *(const bf16x8*)&Hm[hr][(16 + ml) * HSTR + ko_];  \
            }                                                                  \
        }
    // D = W' * A' — same 6 products, same order per acc chain as R9-R27
#define GEMM6X(B, CB, NT)                                                      \
        {                                                                      \
            acc[0][NT] = __builtin_amdgcn_mfma_f32_16x16x32_bf16(B[0], ah[CB][0], acc[0][NT], 0, 0, 0); \
            acc[0][NT] = __builtin_amdgcn_mfma_f32_16x16x32_bf16(B[0], al[CB][0], acc[0][NT], 0, 0, 0); \
            acc[0][NT] = __builtin_amdgcn_mfma_f32_16x16x32_bf16(B[1], ah[CB][0], acc[0][NT], 0, 0, 0); \
            acc[0][NT] = __builtin_amdgcn_mfma_f32_16x16x32_bf16(B[1], al[CB][0], acc[0][NT], 0, 0, 0); \
            acc[0][NT] = __builtin_amdgcn_mfma_f32_16x16x32_bf16(B[2], ah[CB][0], acc[0][NT], 0, 0, 0); \
            acc[0][NT] = __builtin_amdgcn_mfma_f32_16x16x32_bf16(B[0], am[CB][0], acc[0][NT], 0, 0, 0); \
            acc[1][NT] = __builtin_amdgcn_mfma_f32_16x16x32_bf16(B[0], ah[CB][1], acc[1][NT], 0, 0, 0); \
            acc[1][NT] = __builtin_amdgcn_mfma_f32_16x16x32_bf16(B[0], al[CB][1], acc[1][NT], 0, 0, 0); \
            acc[1][NT] = __builtin_amdgcn_mfma_f32_16x16x32_bf16(B[1], ah[CB][1], acc[1][NT], 0, 0, 0); \
            acc[1][NT] = __builtin_amdgcn_mfma_f32_16x16x32_bf16(B[1], al[CB][1], acc[1][NT], 0, 0, 0); \
            acc[1][NT] = __builtin_amdgcn_mfma_f32_16x16x32_bf16(B[2], ah[CB][1], acc[1][NT], 0, 0, 0); \
            acc[1][NT] = __builtin_amdgcn_mfma_f32_16x16x32_bf16(B[0], am[CB][1], acc[1][NT], 0, 0, 0); \
        }

    // W ping-pong buffers live across the whole step loop; prefetch the
    // first half (nt01, Ks=0) now — stays in flight across the barrier.
    bf16x8 wX[2][3], wY[2][3];
    WLOAD(wX[0], Wn[0], 0)
    WLOAD(wX[1], Wn[1], 0)

    __syncthreads();   // F(0) + LDS init visible

    for (int step = 0; step < LL; ++step) {
        const int fb = step & 1;
        const int hw = step & 1;        // h_step is written here
        const int hr = hw ^ 1;          // h_{step-1} lives here (zeros at step 0)

        f32x4 acc[2][4];
        #pragma unroll
        for (int mt = 0; mt < 2; ++mt)
            #pragma unroll
            for (int nt = 0; nt < 4; ++nt)
                acc[mt][nt] = (f32x4){0.f, 0.f, 0.f, 0.f};

        {
            // prime the A pipeline: round 0's planes
            bf16x8 ah[2][2], al[2][2], am[2][2];
            LDA(0, 0)

            #pragma unroll
            for (int Ks = 0; Ks < 11; ++Ks) {
                const int cb = Ks & 1, nb = cb ^ 1;

                // ---- first half: MFMA wX=(nt01,Ks); load wY<-(nt23,Ks) ----
                WLOAD(wY[0], Wn[2], Ks)
                WLOAD(wY[1], Wn[3], Ks)
                // next-round A planes (6 ds_reads; drain under the MFMAs)
                if (Ks < 10) LDA(nb, Ks + 1)

                __builtin_amdgcn_s_setprio(1);
                GEMM6X(wX[0], cb, 0)
                GEMM6X(wX[1], cb, 1)
                __builtin_amdgcn_s_setprio(0);

                // ---- second half: MFMA wY=(nt23,Ks); load wX<-(nt01,Ks+1) --
                if (Ks < 10) {
                    WLOAD(wX[0], Wn[0], Ks + 1)
                    WLOAD(wX[1], Wn[1], Ks + 1)
                }
                __builtin_amdgcn_s_setprio(1);
                GEMM6X(wY[0], cb, 2)
                GEMM6X(wY[1], cb, 3)
                __builtin_amdgcn_s_setprio(0);

                // Two-point wave-staggered features(t+1) in the MFMA shadow:
                // even waves at Ks=4, odd waves at Ks=8. Writes F[fb^1],
                // disjoint from this step's F[fb] reads.
                if (Ks == 4 && step + 1 < LL && (wv & 1) == 0) {
                    const int lnext = d ? (LL - 2 - step) : (step + 1);
                    FEAT_ALL(lnext, fb ^ 1)
                }
                if (Ks == 8 && step + 1 < LL && (wv & 1) == 1) {
                    const int lnext = d ? (LL - 2 - step) : (step + 1);
                    FEAT_ALL(lnext, fb ^ 1)
                }
            }
        }

        // emissions for step-1 (reads H[hr] = h_{step-1}; gates write H[hw])
        if (step > 0 && tid < 192) {
            const int lprev = d ? (LL - step) : (step - 1);
            EMIS_BODY(lprev, hr)
        }

        // gates in-register -> h into H[hw] (nobody reads H[hw] this step)
        #pragma unroll
        for (int mt = 0; mt < 2; ++mt) {
            #pragma unroll
            for (int nt = 0; nt < 4; ++nt) {
                float zi = acc[mt][nt][0] + bIv[nt];
                float zf = acc[mt][nt][1] + bFv[nt];
                float zg = acc[mt][nt][2] + bGv[nt];
                float zo = acc[mt][nt][3] + bOv[nt];
                float cn = sigm(zf) * cst[mt][nt] + sigm(zi) * tanh_fast(zg);
                cst[mt][nt] = cn;
                float h = sigm(zo) * tanh_fast(cn);
                unsigned short h0 = f2bf(h);
                float r1 = h - bf2f(h0);
                unsigned short h1 = f2bf(r1);
                unsigned short h2 = f2bf(r1 - bf2f(h1));
                int idx = (mt * 16 + ml) * HSTR + un[nt];
                Hh[hw][idx] = h0;
                Hl[hw][idx] = h1;
                Hm[hw][idx] = h2;
            }
        }

        // prefetch next step's first half (nt01, Ks=0); stays in flight
        // across the barrier (wX was fully consumed by round 10's first half).
        if (step + 1 < LL) {
            WLOAD(wX[0], Wn[0], 0)
            WLOAD(wX[1], Wn[1], 0)
        }

        __syncthreads();   // h_step + F(t+1) visible; H[hr]/F[fb] free for reuse
    }
#undef GEMM6X
#undef LDA
#undef WLOAD

    // epilogue: emissions for the last step (h_{LL-1} lives in H[(LL-1)&1])
    if (tid < 192) {
        const int llast = d ? 0 : (LL - 1);
        const int hl_ = (LL - 1) & 1;
        EMIS_BODY(llast, hl_)
    }
#undef EMIS_BODY
#undef FEAT_ALL
#undef FEAT_ONE
}

// ---------------------------------------------------------------------------
// Kernel 3: Viterbi decode. R28: LDS-staged + coalesced.
// Old version: 4096 threads (64 waves total), each reading eF/eB at
// stride-360B — 64 cache lines per wave-load, 6 loads x 30 steps of
// latency-exposed L2 traffic at near-zero occupancy. New: 64 rows/block
// (grid 64); block streams eF+eB (fully consecutive, 23KB) and the mask
// column into LDS, then each thread runs its row's DP from LDS (stride-90
// floats = 2-way bank aliasing = free, m136). FP order preserved:
// e = (eF+eB)+eb exactly as before; only step-0's start_t association
// shifts by <=1 ulp (tags survived bf16 emission error, so harmless).
// ---------------------------------------------------------------------------
__global__ __launch_bounds__(VROWS)
void viterbi_kernel(const int* __restrict__ x, const float* __restrict__ ws,
                    const float* __restrict__ trans,
                    const float* __restrict__ start_t,
                    const float* __restrict__ end_t,
                    float* __restrict__ out)
{
    __shared__ float e_s[VROWS * LL * TT];   // 64*90 floats = 23KB
    __shared__ int   m_s[VROWS * LL];        // 64*30 ints  = 7.7KB

    const int tidl = threadIdx.x;
    const int b0   = blockIdx.x * VROWS;

    const float* eF = ws + WS_EMIS;
    const float* eB = ws + WS_EMIS + BB * LL * TT;

    // coalesced stage: e = eF + eB (consecutive addresses)
    for (int i = tidl; i < VROWS * LL * TT; i += VROWS)
        e_s[i] = eF[b0 * LL * TT + i] + eB[b0 * LL * TT + i];
    // mask column (stride-5 within a row: ~coalesced)
    for (int i = tidl; i < VROWS * LL; i += VROWS) {
        int r = i / LL, l = i % LL;
        m_s[i] = x[(((b0 + r) * LL) + l) * WW + 2];
    }
    __syncthreads();

    const int b = b0 + tidl;
    const float* e  = &e_s[tidl * LL * TT];
    const int*   mk = &m_s[tidl * LL];
    const float eb0 = ws[WS_EB + 0], eb1 = ws[WS_EB + 1], eb2 = ws[WS_EB + 2];
    float tr[9];
    #pragma unroll
    for (int i = 0; i < 9; ++i) tr[i] = trans[i];

    float s0 = start_t[0] + e[0] + eb0;
    float s1 = start_t[1] + e[1] + eb1;
    float s2 = start_t[2] + e[2] + eb2;

    unsigned hist[LL - 1];
    unsigned maskbits = 0;

    #pragma unroll
    for (int l = 1; l < LL; ++l) {
        bool m = mk[l] > 0;
        if (m) maskbits |= (1u << l);
        float e0 = e[l * TT + 0] + eb0;
        float e1 = e[l * TT + 1] + eb1;
        float e2 = e[l * TT + 2] + eb2;

        float ns[3]; int pt[3];
        #pragma unroll
        for (int nt = 0; nt < 3; ++nt) {
            float c0 = s0 + tr[0 * 3 + nt];
            float c1 = s1 + tr[1 * 3 + nt];
            float c2 = s2 + tr[2 * 3 + nt];
            int p = 0; float bc = c0;
            if (c1 > bc) { bc = c1; p = 1; }   // strict '>': first-index argmax
            if (c2 > bc) { bc = c2; p = 2; }
            ns[nt] = bc; pt[nt] = p;
        }
        ns[0] += e0; ns[1] += e1; ns[2] += e2;
        hist[l - 1] = (unsigned)pt[0] | ((unsigned)pt[1] << 2) | ((unsigned)pt[2] << 4);
        if (m) { s0 = ns[0]; s1 = ns[1]; s2 = ns[2]; }
    }
    s0 += end_t[0]; s1 += end_t[1]; s2 += end_t[2];
    float best = s0; int last = 0;
    if (s1 > best) { best = s1; last = 1; }
    if (s2 > best) { best = s2; last = 2; }

    out[b] = best;
    float* tags = out + BB + b * LL;
    int tag = last;
    tags[LL - 1] = (float)last;
    #pragma unroll
    for (int l = LL - 1; l >= 1; --l) {
        int prev = (int)((hist[l - 1] >> (2 * tag)) & 3u);
        if (maskbits & (1u << l)) tag = prev;
        tags[l - 1] = (float)tag;
    }
}

// ---------------------------------------------------------------------------
extern "C" void kernel_launch(void* const* d_in, const int* in_sizes, int n_in,
                              void* d_out, int out_size, void* d_ws, size_t ws_size,
                              hipStream_t stream)
{
    const int*   x      = (const int*)  d_in[0];
    const float* emb    = (const float*)d_in[1];
    const float* conv_w = (const float*)d_in[2];
    const float* conv_b = (const float*)d_in[3];
    const float* bn1_g  = (const float*)d_in[4];
    const float* bn1_b  = (const float*)d_in[5];
    const float* bn1_m  = (const float*)d_in[6];
    const float* bn1_v  = (const float*)d_in[7];
    const float* w_ih_f = (const float*)d_in[8];
    const float* w_hh_f = (const float*)d_in[9];
    const float* b_f    = (const float*)d_in[10];
    const float* w_ih_b = (const float*)d_in[11];
    const float* w_hh_b = (const float*)d_in[12];
    const float* b_b    = (const float*)d_in[13];
    const float* bn2_g  = (const float*)d_in[14];
    const float* bn2_b  = (const float*)d_in[15];
    const float* bn2_m  = (const float*)d_in[16];
    const float* bn2_v  = (const float*)d_in[17];
    const float* fc_w   = (const float*)d_in[18];
    const float* fc_b   = (const float*)d_in[19];
    const float* trans  = (const float*)d_in[20];
    const float* start_t= (const float*)d_in[21];
    const float* end_t  = (const float*)d_in[22];

    float* ws  = (float*)d_ws;
    float* out = (float*)d_out;

    prep_kernel<<<256, 256, 0, stream>>>(emb, conv_w, conv_b,
                                         bn1_g, bn1_b, bn1_m, bn1_v,
                                         w_ih_f, w_hh_f, b_f,
                                         w_ih_b, w_hh_b, b_b,
                                         bn2_g, bn2_b, bn2_m, bn2_v,
                                         fc_w, fc_b, ws);
    lstm_kernel<<<256, 512, 0, stream>>>(x, ws);
    viterbi_kernel<<<BB / VROWS, VROWS, 0, stream>>>(x, ws, trans, start_t, end_t, out);
}

// Round 13
// 694.285 us; speedup vs baseline: 1.0956x; 1.0073x over previous
//
#include <hip/hip_runtime.h>
#include <math.h>

// Problem constants
#define BB    4096   // batch
#define LL    30     // seq len
#define WW    5      // window
#define CC    40     // conv channels
#define HH    128    // lstm units
#define TT    3      // crf tags
#define KA    328    // 200 (features) + 128 (h)
#define NB    32     // batch rows per LSTM block
#define NT_   512    // threads per block (8 waves -> 2 waves/SIMD -> no spill)
#define FSTR  232    // F row stride (u16): 7 K-chunks = 224 cols (200 real + 24 pad)
#define HSTR  136    // H row stride (u16): 128 cols + pad (16B-aligned rows)
#define CW    1056   // per-column W footprint in ushorts: 11 Ks * 3 s * 32 k
#define VROWS 64     // viterbi rows per block (LDS-staged coalesced)

// Workspace layout (in floats)
#define WS_P    0                         // P'[3][30][40] conv collapsed + bn1 folded
#define WS_BC   3600                      // biasC[40]
#define WS_BG   3648                      // biasG[2][512]
#define WS_WFC  4672                      // Wfc[2][3][128]  (fc folded with bn2)
#define WS_EB   5440                      // ebias[3]
#define WS_WBF  5504                      // bf16 W [d][n][Ks][s][32]: 540672 floats
#define WS_EMIS (5504 + 540672)           // emis[2][B][L][3] partial emissions

typedef __bf16 bf16x8 __attribute__((ext_vector_type(8)));
typedef float  f32x4  __attribute__((ext_vector_type(4)));
typedef unsigned short u16x8 __attribute__((ext_vector_type(8)));

__device__ __forceinline__ float sigm(float x) {
    return __builtin_amdgcn_rcpf(1.0f + __expf(-x));
}
__device__ __forceinline__ float tanh_fast(float x) {
    return 2.0f * __builtin_amdgcn_rcpf(1.0f + __expf(-2.0f * x)) - 1.0f;
}
// bf16 round-to-nearest-even helpers
__device__ __forceinline__ unsigned short f2bf(float f) {
    unsigned u = __builtin_bit_cast(unsigned, f);
    return (unsigned short)((u + 0x7FFFu + ((u >> 16) & 1u)) >> 16);
}
__device__ __forceinline__ float bf2f(unsigned short h) {
    unsigned u = ((unsigned)h) << 16;
    return __builtin_bit_cast(float, u);
}

// ---------------------------------------------------------------------------
// Kernel 1: fold BN1 into conv tables, 3-term split-bf16 repack of LSTM
// weights ([d][n][Ks][s][32]), fold BN2 into FC.
// R29: W-repack restructured TASK-BASED — one task = one (d,n,Ks,s) group
// of 32 consecutive k's (2*512*33 = 33792 tasks). The old per-element loop
// paid ~5 non-pow2 div/mod chains per u16 (1.08M elements ~= 40+ us of
// addressing); now the div chains run once per 32 outputs, the k-loop is
// contiguous (coalesced wih reads, coalesced writes), and the split-term
// chain is specialized per s. Output values and locations BIT-IDENTICAL
// to R28's loop.
// ---------------------------------------------------------------------------
__global__ void prep_kernel(const float* __restrict__ emb, const float* __restrict__ conv_w,
                            const float* __restrict__ conv_b,
                            const float* __restrict__ bn1_g, const float* __restrict__ bn1_b,
                            const float* __restrict__ bn1_m, const float* __restrict__ bn1_v,
                            const float* __restrict__ w_ih_f, const float* __restrict__ w_hh_f,
                            const float* __restrict__ b_f,
                            const float* __restrict__ w_ih_b, const float* __restrict__ w_hh_b,
                            const float* __restrict__ b_b,
                            const float* __restrict__ bn2_g, const float* __restrict__ bn2_b,
                            const float* __restrict__ bn2_m, const float* __restrict__ bn2_v,
                            const float* __restrict__ fc_w, const float* __restrict__ fc_b,
                            float* __restrict__ ws)
{
    const int gid = blockIdx.x * blockDim.x + threadIdx.x;
    const int gsz = gridDim.x * blockDim.x;

    for (int idx = gid; idx < 3600; idx += gsz) {
        int k = idx / 1200, rem = idx % 1200, a = rem / 40, c = rem % 40;
        float s1 = bn1_g[c] / sqrtf(bn1_v[c] + 1e-5f);
        float acc = 0.f;
        for (int e = 0; e < 128; ++e)
            acc += emb[a * 128 + e] * conv_w[(c * 128 + e) * 3 + k];
        ws[WS_P + idx] = acc * s1;
    }
    for (int c = gid; c < CC; c += gsz) {
        float s1 = bn1_g[c] / sqrtf(bn1_v[c] + 1e-5f);
        ws[WS_BC + c] = (conv_b[c] - bn1_m[c]) * s1 + bn1_b[c];
    }
    for (int i = gid; i < 1024; i += gsz) {
        int d = i >> 9, g = i & 511;
        ws[WS_BG + i] = d ? b_b[g] : b_f[g];
    }
    for (int i = gid; i < 768; i += gsz) {
        int d = i / 384, r = i % 384, t = r / 128, u = r % 128;
        int j = d * 128 + u;
        float s2 = bn2_g[j] / sqrtf(bn2_v[j] + 1e-5f);
        ws[WS_WFC + i] = fc_w[t * 256 + j] * s2;
    }
    for (int t = gid; t < TT; t += gsz) {
        float acc = fc_b[t];
        for (int j = 0; j < 256; ++j) {
            float s2 = bn2_g[j] / sqrtf(bn2_v[j] + 1e-5f);
            acc += fc_w[t * 256 + j] * (bn2_b[j] - bn2_m[j] * s2);
        }
        ws[WS_EB + t] = acc;
    }
    // Wbf[d][n][Ks][s][32]: task-based repack. n = 4u+g4; within a column
    // byte order is Ks-major then s then k32 (offset = (Ks*3+s)*32 + k32).
    unsigned short* wsu = (unsigned short*)ws;
    for (int t = gid; t < 2 * 512 * 33; t += gsz) {
        int d  = t / 16896, r = t - d * 16896;     // 512*33 = 16896
        int n  = r / 33,    g = r - n * 33;        // g = Ks*3 + s
        int Ks = g / 3,     s = g - Ks * 3;
        int u  = n >> 2, q4 = n & 3, row = q4 * 128 + u;
        const float* wih = d ? w_ih_b : w_ih_f;
        const float* whh = d ? w_hh_b : w_hh_f;
        unsigned short* dst = wsu + 2 * WS_WBF + (d * 512 + n) * CW + g * 32;
        for (int k32 = 0; k32 < 32; ++k32) {
            int k = Ks * 32 + k32;
            float w = (k < 200) ? wih[row * 200 + k]
                                : ((k >= 224) ? whh[row * 128 + (k - 224)] : 0.f);
            unsigned short t0 = f2bf(w);
            unsigned short val;
            if (s == 0) {
                val = t0;
            } else {
                float r1 = w - bf2f(t0);
                unsigned short t1 = f2bf(r1);
                val = (s == 1) ? t1 : f2bf(r1 - bf2f(t1));
            }
            dst[k32] = val;
        }
    }
}

// ---------------------------------------------------------------------------
// Kernel 2: fused features + BiLSTM (3-term split-bf16 MFMA) + emissions.
// R23 structure (verified best; R27 A/B showed setprio is load-bearing +6%:
// the FEAT stagger at Ks=4/8 gives co-resident waves role diversity — T5's
// prerequisite). Schedule ledger exhausted: R18/R20/R21/R22/R26 spilled
// (register pool 2048/CU), R24/R25 null-to-negative, R27 regressed.
//  * W ping-pong wX/wY[2][3]; A-plane double buffer; 2-site FEAT stagger
//    (even waves Ks=4, odd Ks=8); emissions + gates post-loop;
//    cross-barrier Ks0 W prefetch; setprio(1/0) around MFMA clusters.
// Numerics bitwise identical to R9-R28. LDS 157,408 B (1 block/CU),
// 8 waves, 2/SIMD, VGPR ~120 (no spill).
// ---------------------------------------------------------------------------
__global__ __launch_bounds__(512, 2)
void lstm_kernel(const int* __restrict__ x, float* __restrict__ ws)
{
    __shared__ unsigned short Fh[2][NB * FSTR], Fl[2][NB * FSTR], Fm[2][NB * FSTR];
    __shared__ unsigned short Hh[2][NB * HSTR], Hl[2][NB * HSTR], Hm[2][NB * HSTR];
    __shared__ float Pp_s[3600];
    __shared__ float Wfc_s[384];
    __shared__ float biasC_s[40];

    const int tid = threadIdx.x;
    const int d   = blockIdx.x & 1;
    const int b0  = (blockIdx.x >> 1) * NB;

    const unsigned short* __restrict__ Wb =
        (const unsigned short*)ws + 2 * WS_WBF + d * (512 * CW);
    float* emis = ws + WS_EMIS + d * (BB * LL * TT);

    for (int i = tid; i < 3600; i += NT_) Pp_s[i] = ws[WS_P + i];
    for (int i = tid; i < 384;  i += NT_) Wfc_s[i] = ws[WS_WFC + d * 384 + i];
    for (int i = tid; i < 40;   i += NT_) biasC_s[i] = ws[WS_BC + i];
    // zero F (both buffers; covers K pads) and H (both buffers; h_{-1}=0)
    for (int i = tid; i < NB * FSTR; i += NT_) {
        ((unsigned*)Fh)[i] = 0u; ((unsigned*)Fl)[i] = 0u; ((unsigned*)Fm)[i] = 0u;
    }
    for (int i = tid; i < NB * HSTR; i += NT_) {
        ((unsigned*)Hh)[i] = 0u; ((unsigned*)Hl)[i] = 0u; ((unsigned*)Hm)[i] = 0u;
    }

    const int lane = tid & 63;
    const int wv   = tid >> 6;          // 0..7: N-tile group (gate-cols 64*wv..)
    const int quad = lane >> 4;
    const int ml   = lane & 15;

    // 4 W base pointers, one per nt; all further offsets are immediates.
    const unsigned short* __restrict__ Wn[4] = {
        Wb + (wv * 64 +  0 + ml) * CW + quad * 8,
        Wb + (wv * 64 + 16 + ml) * CW + quad * 8,
        Wb + (wv * 64 + 32 + ml) * CW + quad * 8,
        Wb + (wv * 64 + 48 + ml) * CW + quad * 8
    };

    // this lane's units (one per nt) and their gate biases
    const float* bgp = ws + WS_BG + d * 512;
    int   un[4];
    float bIv[4], bFv[4], bGv[4], bOv[4];
    #pragma unroll
    for (int nt = 0; nt < 4; ++nt) {
        int u = wv * 16 + nt * 4 + quad;
        un[nt]  = u;
        bIv[nt] = bgp[u];
        bFv[nt] = bgp[128 + u];
        bGv[nt] = bgp[256 + u];
        bOv[nt] = bgp[384 + u];
    }

    float cst[2][4];
    #pragma unroll
    for (int mt = 0; mt < 2; ++mt)
        #pragma unroll
        for (int nt = 0; nt < 4; ++nt) cst[mt][nt] = 0.f;

    __syncthreads();

    // ---- one feature item (batch bb, channel c) for seq position l ----
#define FEAT_ONE(LPOS, BUF, P)                                                 \
    {                                                                          \
        int bb = (P) / CC, c = (P) % CC;                                       \
        const int* tok = x + (((b0 + bb) * LL) + (LPOS)) * WW;                 \
        int t0 = tok[0], t1 = tok[1], t2 = tok[2], t3 = tok[3], t4 = tok[4];   \
        float bc = biasC_s[c];                                                 \
        float a0 = bc + Pp_s[(30 + t0) * 40 + c] + Pp_s[(60 + t1) * 40 + c];   \
        float a1 = bc + Pp_s[t0 * 40 + c] + Pp_s[(30 + t1) * 40 + c] + Pp_s[(60 + t2) * 40 + c]; \
        float a2 = bc + Pp_s[t1 * 40 + c] + Pp_s[(30 + t2) * 40 + c] + Pp_s[(60 + t3) * 40 + c]; \
        float a3 = bc + Pp_s[t2 * 40 + c] + Pp_s[(30 + t3) * 40 + c] + Pp_s[(60 + t4) * 40 + c]; \
        float a4 = bc + Pp_s[t3 * 40 + c] + Pp_s[(30 + t4) * 40 + c];          \
        a0 = fmaxf(a0, 0.f); a1 = fmaxf(a1, 0.f); a2 = fmaxf(a2, 0.f);         \
        a3 = fmaxf(a3, 0.f); a4 = fmaxf(a4, 0.f);                              \
        float f[5];                                                            \
        f[0] = fmaxf(a0, a1);                                                  \
        f[1] = fmaxf(fmaxf(a0, a1), a2);                                       \
        f[2] = fmaxf(fmaxf(a1, a2), a3);                                       \
        f[3] = fmaxf(fmaxf(a2, a3), a4);                                       \
        f[4] = fmaxf(a3, a4);                                                  \
        int base = bb * FSTR + c * 5;                                          \
        _Pragma("unroll")                                                      \
        for (int j = 0; j < 5; ++j) {                                          \
            unsigned short h0 = f2bf(f[j]);                                    \
            float r1 = f[j] - bf2f(h0);                                        \
            unsigned short h1 = f2bf(r1);                                      \
            unsigned short h2 = f2bf(r1 - bf2f(h1));                           \
            Fh[BUF][base + j] = h0;                                            \
            Fl[BUF][base + j] = h1;                                            \
            Fm[BUF][base + j] = h2;                                            \
        }                                                                      \
    }

    // all feature items for this thread: 1280 items over 512 threads.
#define FEAT_ALL(LPOS, BUF)                                                    \
    {                                                                          \
        FEAT_ONE(LPOS, BUF, tid)                                               \
        FEAT_ONE(LPOS, BUF, tid + 512)                                         \
        if (tid >= 256) FEAT_ONE(LPOS, BUF, tid + 768)                         \
    }

    // emissions for one seq position from H buffer HB (threads 0..191)
#define EMIS_BODY(LPOS, HB)                                                    \
    {                                                                          \
        int bb = tid / 6, r6 = tid % 6, t = r6 >> 1, seg = r6 & 1;             \
        int hoff = bb * HSTR + seg * 64;                                       \
        const float* wfc = &Wfc_s[t * 128 + seg * 64];                         \
        float s = 0.f;                                                         \
        _Pragma("unroll")                                                      \
        for (int i = 0; i < 8; ++i) {                                          \
            u16x8 v0 = *(const u16x8*)&Hh[HB][hoff + i * 8];                   \
            u16x8 v1 = *(const u16x8*)&Hl[HB][hoff + i * 8];                   \
            u16x8 v2 = *(const u16x8*)&Hm[HB][hoff + i * 8];                   \
            _Pragma("unroll")                                                  \
            for (int j = 0; j < 8; ++j) {                                      \
                float h = bf2f(v0[j]) + bf2f(v1[j]) + bf2f(v2[j]);             \
                s += h * wfc[i * 8 + j];                                       \
            }                                                                  \
        }                                                                      \
        s += __shfl_xor(s, 1);                                                 \
        if (seg == 0)                                                          \
            emis[(((b0 + bb) * LL) + (LPOS)) * TT + t] = s;                    \
    }

    // prologue: features for step 0
    {
        const int l0 = d ? (LL - 1) : 0;
        FEAT_ALL(l0, 0)
    }

#define WLOAD(B, P, KS)                                                        \
        {                                                                      \
            B[0] = *(const bf16x8*)((P) + (KS) * 96);                          \
            B[1] = *(const bf16x8*)((P) + (KS) * 96 + 32);                     \
            B[2] = *(const bf16x8*)((P) + (KS) * 96 + 64);                     \
        }
    // A-plane loads (all 3 split terms, both m-tiles) for round KS -> buf BUF
#define LDA(BUF, KS)                                                           \
        {                                                                      \
            if ((KS) < 7) {                                                    \
                const int ko_ = (KS) * 32 + quad * 8;                          \
                ah[BUF][0] = *(const bf16x8*)&Fh[fb][ml * FSTR + ko_];         \
                al[BUF][0] = *(const bf16x8*)&Fl[fb][ml * FSTR + ko_];         \
                am[BUF][0] = *(const bf16x8*)&Fm[fb][ml * FSTR + ko_];         \
                ah[BUF][1] = *(const bf16x8*)&Fh[fb][(16 + ml) * FSTR + ko_];  \
                al[BUF][1] = *(const bf16x8*)&Fl[fb][(16 + ml) * FSTR + ko_];  \
                am[BUF][1] = *(const bf16x8*)&Fm[fb][(16 + ml) * FSTR + ko_];  \
            } else {                                                           \
                const int ko_ = ((KS) - 7) * 32 + quad * 8;                    \
                ah[BUF][0] = *(const bf16x8*)&Hh[hr][ml * HSTR + ko_];         \
                al[BUF][0] = *(const bf16x8*)&Hl[hr][ml * HSTR + ko_];         \
                am[BUF][0] = *(const bf16x8*)&Hm[hr][ml * HSTR + ko_];         \
                ah[BUF][1] = *(const bf16x8*)&Hh[hr][(16 + ml) * HSTR + ko_];  \
                al[BUF][1] = *(const bf16x8*)&Hl[hr][(16 + ml) * HSTR + ko_];  \
                am[BUF][1] = *(const bf16x8*)&Hm[hr][(16 + ml) * HSTR + ko_];  \
            }                                                                  \
        }
    // D = W' * A' — same 6 products, same order per acc chain as R9-R28
#define GEMM6X(B, CB, NT)                                                      \
        {                                                                      \
            acc[0][NT] = __builtin_amdgcn_mfma_f32_16x16x32_bf16(B[0], ah[CB][0], acc[0][NT], 0, 0, 0); \
            acc[0][NT] = __builtin_amdgcn_mfma_f32_16x16x32_bf16(B[0], al[CB][0], acc[0][NT], 0, 0, 0); \
            acc[0][NT] = __builtin_amdgcn_mfma_f32_16x16x32_bf16(B[1], ah[CB][0], acc[0][NT], 0, 0, 0); \
            acc[0][NT] = __builtin_amdgcn_mfma_f32_16x16x32_bf16(B[1], al[CB][0], acc[0][NT], 0, 0, 0); \
            acc[0][NT] = __builtin_amdgcn_mfma_f32_16x16x32_bf16(B[2], ah[CB][0], acc[0][NT], 0, 0, 0); \
            acc[0][NT] = __builtin_amdgcn_mfma_f32_16x16x32_bf16(B[0], am[CB][0], acc[0][NT], 0, 0, 0); \
            acc[1][NT] = __builtin_amdgcn_mfma_f32_16x16x32_bf16(B[0], ah[CB][1], acc[1][NT], 0, 0, 0); \
            acc[1][NT] = __builtin_amdgcn_mfma_f32_16x16x32_bf16(B[0], al[CB][1], acc[1][NT], 0, 0, 0); \
            acc[1][NT] = __builtin_amdgcn_mfma_f32_16x16x32_bf16(B[1], ah[CB][1], acc[1][NT], 0, 0, 0); \
            acc[1][NT] = __builtin_amdgcn_mfma_f32_16x16x32_bf16(B[1], al[CB][1], acc[1][NT], 0, 0, 0); \
            acc[1][NT] = __builtin_amdgcn_mfma_f32_16x16x32_bf16(B[2], ah[CB][1], acc[1][NT], 0, 0, 0); \
            acc[1][NT] = __builtin_amdgcn_mfma_f32_16x16x32_bf16(B[0], am[CB][1], acc[1][NT], 0, 0, 0); \
        }

    // W ping-pong buffers live across the whole step loop; prefetch the
    // first half (nt01, Ks=0) now — stays in flight across the barrier.
    bf16x8 wX[2][3], wY[2][3];
    WLOAD(wX[0], Wn[0], 0)
    WLOAD(wX[1], Wn[1], 0)

    __syncthreads();   // F(0) + LDS init visible

    for (int step = 0; step < LL; ++step) {
        const int fb = step & 1;
        const int hw = step & 1;        // h_step is written here
        const int hr = hw ^ 1;          // h_{step-1} lives here (zeros at step 0)

        f32x4 acc[2][4];
        #pragma unroll
        for (int mt = 0; mt < 2; ++mt)
            #pragma unroll
            for (int nt = 0; nt < 4; ++nt)
                acc[mt][nt] = (f32x4){0.f, 0.f, 0.f, 0.f};

        {
            // prime the A pipeline: round 0's planes
            bf16x8 ah[2][2], al[2][2], am[2][2];
            LDA(0, 0)

            #pragma unroll
            for (int Ks = 0; Ks < 11; ++Ks) {
                const int cb = Ks & 1, nb = cb ^ 1;

                // ---- first half: MFMA wX=(nt01,Ks); load wY<-(nt23,Ks) ----
                WLOAD(wY[0], Wn[2], Ks)
                WLOAD(wY[1], Wn[3], Ks)
                // next-round A planes (6 ds_reads; drain under the MFMAs)
                if (Ks < 10) LDA(nb, Ks + 1)

                __builtin_amdgcn_s_setprio(1);
                GEMM6X(wX[0], cb, 0)
                GEMM6X(wX[1], cb, 1)
                __builtin_amdgcn_s_setprio(0);

                // ---- second half: MFMA wY=(nt23,Ks); load wX<-(nt01,Ks+1) --
                if (Ks < 10) {
                    WLOAD(wX[0], Wn[0], Ks + 1)
                    WLOAD(wX[1], Wn[1], Ks + 1)
                }
                __builtin_amdgcn_s_setprio(1);
                GEMM6X(wY[0], cb, 2)
                GEMM6X(wY[1], cb, 3)
                __builtin_amdgcn_s_setprio(0);

                // Two-point wave-staggered features(t+1) in the MFMA shadow:
                // even waves at Ks=4, odd waves at Ks=8. Writes F[fb^1],
                // disjoint from this step's F[fb] reads.
                if (Ks == 4 && step + 1 < LL && (wv & 1) == 0) {
                    const int lnext = d ? (LL - 2 - step) : (step + 1);
                    FEAT_ALL(lnext, fb ^ 1)
                }
                if (Ks == 8 && step + 1 < LL && (wv & 1) == 1) {
                    const int lnext = d ? (LL - 2 - step) : (step + 1);
                    FEAT_ALL(lnext, fb ^ 1)
                }
            }
        }

        // emissions for step-1 (reads H[hr] = h_{step-1}; gates write H[hw])
        if (step > 0 && tid < 192) {
            const int lprev = d ? (LL - step) : (step - 1);
            EMIS_BODY(lprev, hr)
        }

        // gates in-register -> h into H[hw] (nobody reads H[hw] this step)
        #pragma unroll
        for (int mt = 0; mt < 2; ++mt) {
            #pragma unroll
            for (int nt = 0; nt < 4; ++nt) {
                float zi = acc[mt][nt][0] + bIv[nt];
                float zf = acc[mt][nt][1] + bFv[nt];
                float zg = acc[mt][nt][2] + bGv[nt];
                float zo = acc[mt][nt][3] + bOv[nt];
                float cn = sigm(zf) * cst[mt][nt] + sigm(zi) * tanh_fast(zg);
                cst[mt][nt] = cn;
                float h = sigm(zo) * tanh_fast(cn);
                unsigned short h0 = f2bf(h);
                float r1 = h - bf2f(h0);
                unsigned short h1 = f2bf(r1);
                unsigned short h2 = f2bf(r1 - bf2f(h1));
                int idx = (mt * 16 + ml) * HSTR + un[nt];
                Hh[hw][idx] = h0;
                Hl[hw][idx] = h1;
                Hm[hw][idx] = h2;
            }
        }

        // prefetch next step's first half (nt01, Ks=0); stays in flight
        // across the barrier (wX was fully consumed by round 10's first half).
        if (step + 1 < LL) {
            WLOAD(wX[0], Wn[0], 0)
            WLOAD(wX[1], Wn[1], 0)
        }

        __syncthreads();   // h_step + F(t+1) visible; H[hr]/F[fb] free for reuse
    }
#undef GEMM6X
#undef LDA
#undef WLOAD

    // epilogue: emissions for the last step (h_{LL-1} lives in H[(LL-1)&1])
    if (tid < 192) {
        const int llast = d ? 0 : (LL - 1);
        const int hl_ = (LL - 1) & 1;
        EMIS_BODY(llast, hl_)
    }
#undef EMIS_BODY
#undef FEAT_ALL
#undef FEAT_ONE
}

// ---------------------------------------------------------------------------
// Kernel 3: Viterbi decode. LDS-staged + coalesced (R28; verified +24 us).
// 64 rows/block; block streams eF+eB (fully consecutive, 23KB) and the
// mask column into LDS, then each thread runs its row's DP from LDS
// (stride-90 floats = 2-way bank aliasing = free, m136).
// ---------------------------------------------------------------------------
__global__ __launch_bounds__(VROWS)
void viterbi_kernel(const int* __restrict__ x, const float* __restrict__ ws,
                    const float* __restrict__ trans,
                    const float* __restrict__ start_t,
                    const float* __restrict__ end_t,
                    float* __restrict__ out)
{
    __shared__ float e_s[VROWS * LL * TT];   // 64*90 floats = 23KB
    __shared__ int   m_s[VROWS * LL];        // 64*30 ints  = 7.7KB

    const int tidl = threadIdx.x;
    const int b0   = blockIdx.x * VROWS;

    const float* eF = ws + WS_EMIS;
    const float* eB = ws + WS_EMIS + BB * LL * TT;

    // coalesced stage: e = eF + eB (consecutive addresses)
    for (int i = tidl; i < VROWS * LL * TT; i += VROWS)
        e_s[i] = eF[b0 * LL * TT + i] + eB[b0 * LL * TT + i];
    // mask column (stride-5 within a row: ~coalesced)
    for (int i = tidl; i < VROWS * LL; i += VROWS) {
        int r = i / LL, l = i % LL;
        m_s[i] = x[(((b0 + r) * LL) + l) * WW + 2];
    }
    __syncthreads();

    const int b = b0 + tidl;
    const float* e  = &e_s[tidl * LL * TT];
    const int*   mk = &m_s[tidl * LL];
    const float eb0 = ws[WS_EB + 0], eb1 = ws[WS_EB + 1], eb2 = ws[WS_EB + 2];
    float tr[9];
    #pragma unroll
    for (int i = 0; i < 9; ++i) tr[i] = trans[i];

    float s0 = start_t[0] + e[0] + eb0;
    float s1 = start_t[1] + e[1] + eb1;
    float s2 = start_t[2] + e[2] + eb2;

    unsigned hist[LL - 1];
    unsigned maskbits = 0;

    #pragma unroll
    for (int l = 1; l < LL; ++l) {
        bool m = mk[l] > 0;
        if (m) maskbits |= (1u << l);
        float e0 = e[l * TT + 0] + eb0;
        float e1 = e[l * TT + 1] + eb1;
        float e2 = e[l * TT + 2] + eb2;

        float ns[3]; int pt[3];
        #pragma unroll
        for (int nt = 0; nt < 3; ++nt) {
            float c0 = s0 + tr[0 * 3 + nt];
            float c1 = s1 + tr[1 * 3 + nt];
            float c2 = s2 + tr[2 * 3 + nt];
            int p = 0; float bc = c0;
            if (c1 > bc) { bc = c1; p = 1; }   // strict '>': first-index argmax
            if (c2 > bc) { bc = c2; p = 2; }
            ns[nt] = bc; pt[nt] = p;
        }
        ns[0] += e0; ns[1] += e1; ns[2] += e2;
        hist[l - 1] = (unsigned)pt[0] | ((unsigned)pt[1] << 2) | ((unsigned)pt[2] << 4);
        if (m) { s0 = ns[0]; s1 = ns[1]; s2 = ns[2]; }
    }
    s0 += end_t[0]; s1 += end_t[1]; s2 += end_t[2];
    float best = s0; int last = 0;
    if (s1 > best) { best = s1; last = 1; }
    if (s2 > best) { best = s2; last = 2; }

    out[b] = best;
    float* tags = out + BB + b * LL;
    int tag = last;
    tags[LL - 1] = (float)last;
    #pragma unroll
    for (int l = LL - 1; l >= 1; --l) {
        int prev = (int)((hist[l - 1] >> (2 * tag)) & 3u);
        if (maskbits & (1u << l)) tag = prev;
        tags[l - 1] = (float)tag;
    }
}

// ---------------------------------------------------------------------------
extern "C" void kernel_launch(void* const* d_in, const int* in_sizes, int n_in,
                              void* d_out, int out_size, void* d_ws, size_t ws_size,
                              hipStream_t stream)
{
    const int*   x      = (const int*)  d_in[0];
    const float* emb    = (const float*)d_in[1];
    const float* conv_w = (const float*)d_in[2];
    const float* conv_b = (const float*)d_in[3];
    const float* bn1_g  = (const float*)d_in[4];
    const float* bn1_b  = (const float*)d_in[5];
    const float* bn1_m  = (const float*)d_in[6];
    const float* bn1_v  = (const float*)d_in[7];
    const float* w_ih_f = (const float*)d_in[8];
    const float* w_hh_f = (const float*)d_in[9];
    const float* b_f    = (const float*)d_in[10];
    const float* w_ih_b = (const float*)d_in[11];
    const float* w_hh_b = (const float*)d_in[12];
    const float* b_b    = (const float*)d_in[13];
    const float* bn2_g  = (const float*)d_in[14];
    const float* bn2_b  = (const float*)d_in[15];
    const float* bn2_m  = (const float*)d_in[16];
    const float* bn2_v  = (const float*)d_in[17];
    const float* fc_w   = (const float*)d_in[18];
    const float* fc_b   = (const float*)d_in[19];
    const float* trans  = (const float*)d_in[20];
    const float* start_t= (const float*)d_in[21];
    const float* end_t  = (const float*)d_in[22];

    float* ws  = (float*)d_ws;
    float* out = (float*)d_out;

    prep_kernel<<<256, 256, 0, stream>>>(emb, conv_w, conv_b,
                                         bn1_g, bn1_b, bn1_m, bn1_v,
                                         w_ih_f, w_hh_f, b_f,
                                         w_ih_b, w_hh_b, b_b,
                                         bn2_g, bn2_b, bn2_m, bn2_v,
                                         fc_w, fc_b, ws);
    lstm_kernel<<<256, 512, 0, stream>>>(x, ws);
    viterbi_kernel<<<BB / VROWS, VROWS, 0, stream>>>(x, ws, trans, start_t, end_t, out);
}